// Round 3
// 363.663 us; speedup vs baseline: 1.0837x; 1.0837x over previous
//
#include <hip/hip_runtime.h>

#define D_MODEL 2048
#define B_SZ 4
#define T_SZ 2048
#define N_SZ 512

typedef __bf16 bf16x8 __attribute__((ext_vector_type(8)));
typedef float f32x4 __attribute__((ext_vector_type(4)));
typedef ushort u16x8 __attribute__((ext_vector_type(8)));

// fp32 -> bf16 round-to-nearest-even
__device__ __forceinline__ ushort f2bf(float f) {
  unsigned u = __float_as_uint(f);
  unsigned r = (u + 0x7fffu + ((u >> 16) & 1u)) >> 16;
  return (ushort)r;
}
__device__ __forceinline__ float bflo(unsigned w) { return __uint_as_float(w << 16); }
__device__ __forceinline__ float bfhi(unsigned w) { return __uint_as_float(w & 0xffff0000u); }

__device__ __forceinline__ void async_ld16(const ushort* g, ushort* l) {
  __builtin_amdgcn_global_load_lds(
      (const __attribute__((address_space(1))) void*)g,
      (__attribute__((address_space(3))) void*)l, 16, 0, 0);
}

// single fused fp32->bf16 conversion for x (8192 blk), W (2048 blk), m_stack (2048 blk)
__global__ __launch_bounds__(256) void conv_all(const float* __restrict__ x,
                                                const float* __restrict__ W,
                                                const float* __restrict__ ms,
                                                ushort* __restrict__ x_bf,
                                                ushort* __restrict__ W_bf,
                                                ushort* __restrict__ ms_bf) {
  const int bid = blockIdx.x;
  const float* src;
  ushort* dst;
  long blk;
  if (bid < 8192) { src = x; dst = x_bf; blk = bid; }
  else if (bid < 10240) { src = W; dst = W_bf; blk = bid - 8192; }
  else { src = ms; dst = ms_bf; blk = bid - 10240; }
  const long i = (blk * 256 + threadIdx.x) * 8;
  float4 a = *(const float4*)(src + i);
  float4 b = *(const float4*)(src + i + 4);
  u16x8 o;
  o[0] = f2bf(a.x); o[1] = f2bf(a.y); o[2] = f2bf(a.z); o[3] = f2bf(a.w);
  o[4] = f2bf(b.x); o[5] = f2bf(b.y); o[6] = f2bf(b.z); o[7] = f2bf(b.w);
  *(u16x8*)(dst + i) = o;
}

// h_stack (B,N,D) fp32 -> hsT (B,D,N) bf16
__global__ __launch_bounds__(256) void transpose_conv(const float* __restrict__ src,
                                                      ushort* __restrict__ dst) {
  __shared__ ushort tile[32][33];
  const int b = blockIdx.z;
  const int n0 = blockIdx.x * 32, d0 = blockIdx.y * 32;
  const int tx = threadIdx.x, ty = threadIdx.y;  // (32,8)
  const float* s = src + (long)b * N_SZ * D_MODEL;
  ushort* d = dst + (long)b * D_MODEL * N_SZ;
#pragma unroll
  for (int r = 0; r < 4; r++)
    tile[ty + r * 8][tx] = f2bf(s[(long)(n0 + ty + r * 8) * D_MODEL + d0 + tx]);
  __syncthreads();
#pragma unroll
  for (int r = 0; r < 4; r++)
    d[(long)(d0 + ty + r * 8) * N_SZ + n0 + tx] = tile[tx][ty + r * 8];
}

// ---------------------------------------------------------------------------
// legacy 128-col tile GEMM — kept for the scores GEMM (N=512 -> needs the
// finer grid for CU coverage). C[M,N] = A[M,K] * Bt[N,K]^T, bf16 in.
// MASKMODE 1: skip tile if col0 > (t_max>>2).
template <int TM, int MASKMODE, bool OUT_BF16>
__global__ __launch_bounds__(256) void gemm_bt(const ushort* __restrict__ A,
                                               const ushort* __restrict__ Bt,
                                               void* __restrict__ Cv, int N, int K,
                                               long sA, long sB, long sC, float scale) {
  constexpr int NA = TM / 16;   // A-tile 1KB chunks
  constexpr int NCH = NA + 8;   // total chunks (B-tile has 8)
  constexpr int NC = NCH / 4;   // chunks per wave
  constexpr int NI = TM / 32;   // i-blocks per wave
  __shared__ __align__(16) ushort sa[TM * 32];
  __shared__ __align__(16) ushort sb[128 * 32];
  const int bz = blockIdx.z;
  const int row0 = blockIdx.y * TM;
  const int col0 = blockIdx.x * 128;
  if (MASKMODE == 1 && col0 > ((row0 + TM - 1) >> 2)) return;
  int Kend = K;
  if (MASKMODE == 2) {
    int kl = ((row0 + TM - 1) >> 2) + 1;
    Kend = min(K, (kl + 31) & ~31);
  }
  const ushort* Ab = A + (long)bz * sA;
  const ushort* Bb = Bt + (long)bz * sB;

  const int tid = threadIdx.x;
  const int w = tid >> 6, lane = tid & 63;
  const int wr = w >> 1, wc = w & 1;
  const int quad = lane >> 4, l16 = lane & 15;

  f32x4 acc[NI][4];
#pragma unroll
  for (int i = 0; i < NI; i++)
#pragma unroll
    for (int j = 0; j < 4; j++) acc[i][j] = (f32x4){0.f, 0.f, 0.f, 0.f};

  const int lrow = lane >> 2;
  const int lcol = (lane & 3) * 8;
  const ushort* gsrc[NC];
  ushort* ldst[NC];
#pragma unroll
  for (int t = 0; t < NC; t++) {
    const int c = w * NC + t;
    if (c < NA) {
      ldst[t] = sa + c * 512;
      gsrc[t] = Ab + (long)(row0 + c * 16 + lrow) * K + lcol;
    } else {
      ldst[t] = sb + (c - NA) * 512;
      gsrc[t] = Bb + (long)(col0 + (c - NA) * 16 + lrow) * K + lcol;
    }
  }

  for (int k0 = 0; k0 < Kend; k0 += 32) {
#pragma unroll
    for (int t = 0; t < NC; t++) async_ld16(gsrc[t] + k0, ldst[t]);
    __syncthreads();
    bf16x8 af[NI], bfr[4];
#pragma unroll
    for (int i = 0; i < NI; i++)
      af[i] = *(const bf16x8*)(sa + (wr * (TM / 2) + i * 16 + l16) * 32 + quad * 8);
#pragma unroll
    for (int j = 0; j < 4; j++)
      bfr[j] = *(const bf16x8*)(sb + (wc * 64 + j * 16 + l16) * 32 + quad * 8);
#pragma unroll
    for (int i = 0; i < NI; i++)
#pragma unroll
      for (int j = 0; j < 4; j++)
        acc[i][j] = __builtin_amdgcn_mfma_f32_16x16x32_bf16(af[i], bfr[j], acc[i][j], 0, 0, 0);
    __syncthreads();
  }

#pragma unroll
  for (int i = 0; i < NI; i++) {
    const int rb = row0 + wr * (TM / 2) + i * 16 + quad * 4;
#pragma unroll
    for (int j = 0; j < 4; j++) {
      const int c = col0 + wc * 64 + j * 16 + l16;
#pragma unroll
      for (int r = 0; r < 4; r++) {
        float v = acc[i][j][r] * scale;
        long off = (long)bz * sC + (long)(rb + r) * N + c;
        if (OUT_BF16)
          ((ushort*)Cv)[off] = f2bf(v);
        else
          ((float*)Cv)[off] = v;
      }
    }
  }
}

// ---------------------------------------------------------------------------
// 256x256 8-phase GEMM (T2 swizzle + T3/T4 counted vmcnt + T5 setprio).
// BK=64, 8 waves (2M x 4N), wave tile 128x64, 128 KiB double-buffered LDS.
// LDS layout per buffer/operand: [256 rows][64 k] bf16 with ushort-index
// XOR swizzle  idx = row*64 + (col ^ ((row&7)<<3))  -> conflict-free
// ds_read_b128 (rule #21: linear global_load_lds dest + inverse-swizzled
// global SOURCE + swizzled read).
// Per K-tile: 4 phases; each phase stages 1/4 of the next K-tile
// (2 global_load_lds per thread), reads 12 b128 frags, runs 16 MFMA under
// setprio(1). Single s_waitcnt vmcnt(2) per K-tile (never 0 in steady state).
// MASKMODE 2: truncate K to the gates' nonzero range (64-granular).
template <int MASKMODE, bool OUT_BF16>
__global__ __launch_bounds__(512, 2) void gemm256(const ushort* __restrict__ A,
                                                  const ushort* __restrict__ Bt,
                                                  void* __restrict__ Cv, int N, int K,
                                                  long sA, long sB, long sC, float scale) {
  __shared__ __align__(16) ushort lds[2][2][256 * 64];  // [buf][A/B][row*64+col] 128 KiB
  const int bz = blockIdx.z;
  const int row0 = blockIdx.y * 256;
  const int col0 = blockIdx.x * 256;
  int Kend = K;
  if (MASKMODE == 2) {
    int kl = ((row0 + 255) >> 2) + 1;
    Kend = min(K, (kl + 63) & ~63);
  }
  const int NT = Kend >> 6;
  const ushort* Ab = A + (long)bz * sA;
  const ushort* Bb = Bt + (long)bz * sB;

  const int tid = threadIdx.x;
  const int w = tid >> 6, lane = tid & 63;
  const int wr = w >> 2, wc = w & 3;  // 2 x 4 wave grid
  const int quad = lane >> 4, l16 = lane & 15;

  f32x4 acc[8][4];
#pragma unroll
  for (int i = 0; i < 8; i++)
#pragma unroll
    for (int j = 0; j < 4; j++) acc[i][j] = (f32x4){0.f, 0.f, 0.f, 0.f};

  // staging: round j covers LDS rows j*64 + w*8 + (lane>>3); lane%8 picks the
  // 16B chunk. Global col is pre-swizzled so the linear LDS fill realizes the
  // XOR layout: col_ush = ((lane&7) ^ (lane>>3)) * 8.
  const int lrow = lane >> 3;
  const int lcol = ((lane & 7) ^ lrow) << 3;
  const ushort* gA[4];
  const ushort* gB[4];
#pragma unroll
  for (int j = 0; j < 4; j++) {
    gA[j] = Ab + (long)(row0 + j * 64 + w * 8 + lrow) * K + lcol;
    gB[j] = Bb + (long)(col0 + j * 64 + w * 8 + lrow) * K + lcol;
  }

#define GPHASE(MQ, NQ)                                                                   \
  do {                                                                                   \
    bf16x8 af[4][2], bv[2][2];                                                           \
    _Pragma("unroll") for (int m = 0; m < 4; m++) _Pragma("unroll")                      \
        for (int ks = 0; ks < 2; ks++) {                                                 \
      const int row = wr * 128 + MQ * 64 + m * 16 + l16;                                 \
      af[m][ks] = *(const bf16x8*)&lds[cbuf][0]                                          \
          [row * 64 + ((ks * 32 + quad * 8) ^ ((l16 & 7) << 3))];                        \
    }                                                                                    \
    _Pragma("unroll") for (int n = 0; n < 2; n++) _Pragma("unroll")                      \
        for (int ks = 0; ks < 2; ks++) {                                                 \
      const int row = wc * 64 + NQ * 32 + n * 16 + l16;                                  \
      bv[n][ks] = *(const bf16x8*)&lds[cbuf][1]                                          \
          [row * 64 + ((ks * 32 + quad * 8) ^ ((l16 & 7) << 3))];                        \
    }                                                                                    \
    __builtin_amdgcn_s_barrier();                                                        \
    __builtin_amdgcn_s_setprio(1);                                                       \
    _Pragma("unroll") for (int m = 0; m < 4; m++) _Pragma("unroll")                      \
        for (int n = 0; n < 2; n++) _Pragma("unroll")                                    \
            for (int ks = 0; ks < 2; ks++)                                               \
      acc[MQ * 4 + m][NQ * 2 + n] = __builtin_amdgcn_mfma_f32_16x16x32_bf16(             \
          af[m][ks], bv[n][ks], acc[MQ * 4 + m][NQ * 2 + n], 0, 0, 0);                   \
    __builtin_amdgcn_s_setprio(0);                                                       \
    __builtin_amdgcn_s_barrier();                                                        \
  } while (0)

  // prologue: stage K-tile 0 into buffer 0 (8 loads in flight)
#pragma unroll
  for (int j = 0; j < 4; j++) {
    async_ld16(gA[j], &lds[0][0][j * 4096 + w * 512]);
    async_ld16(gB[j], &lds[0][1][j * 4096 + w * 512]);
  }

  for (int t = 0; t < NT; ++t) {
    const int cbuf = t & 1;
    const int kn = (t + 1) << 6;
    // phase 0: stage round 0 of next tile, then the ONLY wait of this K-tile:
    // vmcnt(2) = previous tile fully landed, the 2 fresh loads stay in flight.
    if (t + 1 < NT) {
      async_ld16(gA[0] + kn, &lds[cbuf ^ 1][0][0 * 4096 + w * 512]);
      async_ld16(gB[0] + kn, &lds[cbuf ^ 1][1][0 * 4096 + w * 512]);
      asm volatile("s_waitcnt vmcnt(2)" ::: "memory");
    } else {
      asm volatile("s_waitcnt vmcnt(0)" ::: "memory");
    }
    __builtin_amdgcn_s_barrier();  // all waves' stages for THIS tile visible
    GPHASE(0, 0);
    if (t + 1 < NT) {
      async_ld16(gA[1] + kn, &lds[cbuf ^ 1][0][1 * 4096 + w * 512]);
      async_ld16(gB[1] + kn, &lds[cbuf ^ 1][1][1 * 4096 + w * 512]);
    }
    GPHASE(0, 1);
    if (t + 1 < NT) {
      async_ld16(gA[2] + kn, &lds[cbuf ^ 1][0][2 * 4096 + w * 512]);
      async_ld16(gB[2] + kn, &lds[cbuf ^ 1][1][2 * 4096 + w * 512]);
    }
    GPHASE(1, 0);
    if (t + 1 < NT) {
      async_ld16(gA[3] + kn, &lds[cbuf ^ 1][0][3 * 4096 + w * 512]);
      async_ld16(gB[3] + kn, &lds[cbuf ^ 1][1][3 * 4096 + w * 512]);
    }
    GPHASE(1, 1);
  }
#undef GPHASE

#pragma unroll
  for (int i = 0; i < 8; i++) {
    const int rb = row0 + wr * 128 + (i >> 2) * 64 + (i & 3) * 16 + quad * 4;
#pragma unroll
    for (int j = 0; j < 4; j++) {
      const int cc = col0 + wc * 64 + (j >> 1) * 32 + (j & 1) * 16 + l16;
#pragma unroll
      for (int r = 0; r < 4; r++) {
        float v = acc[i][j][r] * scale;
        long off = (long)bz * sC + (long)(rb + r) * N + cc;
        if (OUT_BF16)
          ((ushort*)Cv)[off] = f2bf(v);
        else
          ((float*)Cv)[off] = v;
      }
    }
  }
}

// one WAVE per (b,t) row: current-score dot + masked softmax over 513.
__global__ __launch_bounds__(256) void softmax_gate(const ushort* __restrict__ u_bf,
                                                    const float* __restrict__ m_cur,
                                                    const float* __restrict__ scores,
                                                    float* __restrict__ out_gc,
                                                    float* __restrict__ out_attn,
                                                    ushort* __restrict__ gates_bf) {
  const int wv = threadIdx.x >> 6, lane = threadIdx.x & 63;
  const int bt = blockIdx.x * 4 + wv;
  const int t = bt & (T_SZ - 1);
  const ushort* urow = u_bf + (long)bt * D_MODEL;
  const float* mrow = m_cur + (long)bt * D_MODEL;

  float part = 0.f;
#pragma unroll
  for (int c = 0; c < 4; c++) {
    uint4 uv = *(const uint4*)(urow + c * 512 + lane * 8);
    float4 m0 = *(const float4*)(mrow + c * 512 + lane * 8);
    float4 m1 = *(const float4*)(mrow + c * 512 + lane * 8 + 4);
    part += bflo(uv.x) * m0.x + bfhi(uv.x) * m0.y + bflo(uv.y) * m0.z + bfhi(uv.y) * m0.w +
            bflo(uv.z) * m1.x + bfhi(uv.z) * m1.y + bflo(uv.w) * m1.z + bfhi(uv.w) * m1.w;
  }
#pragma unroll
  for (int m = 32; m; m >>= 1) part += __shfl_xor(part, m, 64);
  const float curs = part * 0.022097086912079608f;  // 1/sqrt(2048)

  const int nmax = t >> 2;
  const float* srow = scores + (long)bt * N_SZ;
  float sc[8];
  float lmax = curs;
#pragma unroll
  for (int k = 0; k < 8; k++) {
    const int n = k * 64 + lane;
    sc[k] = srow[n];
    if (n <= nmax) lmax = fmaxf(lmax, sc[k]);
  }
#pragma unroll
  for (int m = 32; m; m >>= 1) lmax = fmaxf(lmax, __shfl_xor(lmax, m, 64));

  float lsum = (lane == 0) ? __expf(curs - lmax) : 0.f;
#pragma unroll
  for (int k = 0; k < 8; k++) {
    const int n = k * 64 + lane;
    sc[k] = (n <= nmax) ? __expf(sc[k] - lmax) : 0.f;
    lsum += sc[k];
  }
#pragma unroll
  for (int m = 32; m; m >>= 1) lsum += __shfl_xor(lsum, m, 64);
  const float inv = 1.f / lsum;

  float* arow = out_attn + (long)bt * (N_SZ + 1);
  ushort* grow = gates_bf + (long)bt * N_SZ;
#pragma unroll
  for (int k = 0; k < 8; k++) {
    const int n = k * 64 + lane;
    const float wgt = sc[k] * inv;
    arow[n] = wgt;
    grow[n] = f2bf(wgt);
  }
  if (lane == 0) {
    const float g = __expf(curs - lmax) * inv;
    arow[N_SZ] = g;
    out_gc[bt] = g;
  }
}

extern "C" void kernel_launch(void* const* d_in, const int* in_sizes, int n_in,
                              void* d_out, int out_size, void* d_ws, size_t ws_size,
                              hipStream_t stream) {
  const float* x = (const float*)d_in[0];        // (B,T,D) fp32
  const float* h_stack = (const float*)d_in[1];  // (B,N,D) fp32
  const float* m_stack = (const float*)d_in[2];  // (B,N,D) fp32
  const float* m_cur = (const float*)d_in[3];    // (B,T,D) fp32
  const float* W = (const float*)d_in[5];        // (D,D) fp32  (d_in[4] = mask, recomputed)

  float* out = (float*)d_out;  // fp32 = reference output dtype
  float* out_h = out;                                 // (B,T,D)
  float* out_gc = out + (long)B_SZ * T_SZ * D_MODEL;  // (B,T,1)
  float* out_attn = out_gc + B_SZ * T_SZ;             // (B,T,N+1)

  // workspace layout (112 MB total)
  char* ws = (char*)d_ws;
  ushort* x_bf = (ushort*)ws;               // B*T*D   = 16,777,216
  ushort* u_bf = x_bf + 16777216;           // B*T*D
  ushort* W_bf = u_bf + 16777216;           // D*D     =  4,194,304
  ushort* ms_bf = W_bf + 4194304;           // B*N*D
  ushort* gates = ms_bf + 4194304;          // B*T*N   =  4,194,304
  ushort* hsT = gates + 4194304;            // B*D*N
  float* scores = (float*)(hsT + 4194304);  // B*T*N fp32

  conv_all<<<12288, 256, 0, stream>>>(x, W, m_stack, x_bf, W_bf, ms_bf);
  transpose_conv<<<dim3(N_SZ / 32, D_MODEL / 32, B_SZ), dim3(32, 8), 0, stream>>>(h_stack, hsT);

  // u = x @ W^T  (M=8192, N=2048, K=2048), out bf16. 256 blocks = 1/CU.
  gemm256<0, true><<<dim3(D_MODEL / 256, (B_SZ * T_SZ) / 256, 1), 512, 0, stream>>>(
      x_bf, W_bf, u_bf, D_MODEL, D_MODEL, 0, 0, 0, 1.0f);

  // scores = u @ m_stack^T * scale  per batch (M=2048, N=512, K=2048), fp32 out.
  // stays on the 128-col-tile path: 320 active blocks vs 64 at 256² tiling.
  gemm_bt<64, 1, false><<<dim3(N_SZ / 128, T_SZ / 64, B_SZ), 256, 0, stream>>>(
      u_bf, ms_bf, scores, N_SZ, D_MODEL, (long)T_SZ * D_MODEL, (long)N_SZ * D_MODEL,
      (long)T_SZ * N_SZ, 0.022097086912079608f);

  softmax_gate<<<(B_SZ * T_SZ) / 4, 256, 0, stream>>>(u_bf, m_cur, scores, out_gc, out_attn,
                                                      gates);

  // h = gates @ hsT^T  per batch (M=2048, N=2048, K truncated 64..512), fp32 out
  gemm256<2, false><<<dim3(D_MODEL / 256, T_SZ / 256, B_SZ), 512, 0, stream>>>(
      gates, hsT, out_h, D_MODEL, N_SZ, (long)T_SZ * N_SZ, (long)D_MODEL * N_SZ,
      (long)T_SZ * D_MODEL, 1.0f);
}

// Round 4
// 362.203 us; speedup vs baseline: 1.0881x; 1.0040x over previous
//
#include <hip/hip_runtime.h>

#define D_MODEL 2048
#define B_SZ 4
#define T_SZ 2048
#define N_SZ 512

typedef __bf16 bf16x8 __attribute__((ext_vector_type(8)));
typedef float f32x4 __attribute__((ext_vector_type(4)));
typedef ushort u16x8 __attribute__((ext_vector_type(8)));

// fp32 -> bf16 round-to-nearest-even
__device__ __forceinline__ ushort f2bf(float f) {
  unsigned u = __float_as_uint(f);
  unsigned r = (u + 0x7fffu + ((u >> 16) & 1u)) >> 16;
  return (ushort)r;
}
__device__ __forceinline__ float bflo(unsigned w) { return __uint_as_float(w << 16); }
__device__ __forceinline__ float bfhi(unsigned w) { return __uint_as_float(w & 0xffff0000u); }

__device__ __forceinline__ void async_ld16(const ushort* g, ushort* l) {
  __builtin_amdgcn_global_load_lds(
      (const __attribute__((address_space(1))) void*)g,
      (__attribute__((address_space(3))) void*)l, 16, 0, 0);
}

// single fused fp32->bf16 conversion for x (8192 blk), W (2048 blk), m_stack (2048 blk)
__global__ __launch_bounds__(256) void conv_all(const float* __restrict__ x,
                                                const float* __restrict__ W,
                                                const float* __restrict__ ms,
                                                ushort* __restrict__ x_bf,
                                                ushort* __restrict__ W_bf,
                                                ushort* __restrict__ ms_bf) {
  const int bid = blockIdx.x;
  const float* src;
  ushort* dst;
  long blk;
  if (bid < 8192) { src = x; dst = x_bf; blk = bid; }
  else if (bid < 10240) { src = W; dst = W_bf; blk = bid - 8192; }
  else { src = ms; dst = ms_bf; blk = bid - 10240; }
  const long i = (blk * 256 + threadIdx.x) * 8;
  float4 a = *(const float4*)(src + i);
  float4 b = *(const float4*)(src + i + 4);
  u16x8 o;
  o[0] = f2bf(a.x); o[1] = f2bf(a.y); o[2] = f2bf(a.z); o[3] = f2bf(a.w);
  o[4] = f2bf(b.x); o[5] = f2bf(b.y); o[6] = f2bf(b.z); o[7] = f2bf(b.w);
  *(u16x8*)(dst + i) = o;
}

// h_stack (B,N,D) fp32 -> hsT (B,D,N) bf16
__global__ __launch_bounds__(256) void transpose_conv(const float* __restrict__ src,
                                                      ushort* __restrict__ dst) {
  __shared__ ushort tile[32][33];
  const int b = blockIdx.z;
  const int n0 = blockIdx.x * 32, d0 = blockIdx.y * 32;
  const int tx = threadIdx.x, ty = threadIdx.y;  // (32,8)
  const float* s = src + (long)b * N_SZ * D_MODEL;
  ushort* d = dst + (long)b * D_MODEL * N_SZ;
#pragma unroll
  for (int r = 0; r < 4; r++)
    tile[ty + r * 8][tx] = f2bf(s[(long)(n0 + ty + r * 8) * D_MODEL + d0 + tx]);
  __syncthreads();
#pragma unroll
  for (int r = 0; r < 4; r++)
    d[(long)(d0 + ty + r * 8) * N_SZ + n0 + tx] = tile[tx][ty + r * 8];
}

// ---------------------------------------------------------------------------
// legacy 128-col tile GEMM — kept for the scores GEMM (N=512 -> needs the
// finer grid for CU coverage). C[M,N] = A[M,K] * Bt[N,K]^T, bf16 in.
// MASKMODE 1: skip tile if col0 > (t_max>>2).
template <int TM, int MASKMODE, bool OUT_BF16>
__global__ __launch_bounds__(256) void gemm_bt(const ushort* __restrict__ A,
                                               const ushort* __restrict__ Bt,
                                               void* __restrict__ Cv, int N, int K,
                                               long sA, long sB, long sC, float scale) {
  constexpr int NA = TM / 16;   // A-tile 1KB chunks
  constexpr int NCH = NA + 8;   // total chunks (B-tile has 8)
  constexpr int NC = NCH / 4;   // chunks per wave
  constexpr int NI = TM / 32;   // i-blocks per wave
  __shared__ __align__(16) ushort sa[TM * 32];
  __shared__ __align__(16) ushort sb[128 * 32];
  const int bz = blockIdx.z;
  const int row0 = blockIdx.y * TM;
  const int col0 = blockIdx.x * 128;
  if (MASKMODE == 1 && col0 > ((row0 + TM - 1) >> 2)) return;
  int Kend = K;
  if (MASKMODE == 2) {
    int kl = ((row0 + TM - 1) >> 2) + 1;
    Kend = min(K, (kl + 31) & ~31);
  }
  const ushort* Ab = A + (long)bz * sA;
  const ushort* Bb = Bt + (long)bz * sB;

  const int tid = threadIdx.x;
  const int w = tid >> 6, lane = tid & 63;
  const int wr = w >> 1, wc = w & 1;
  const int quad = lane >> 4, l16 = lane & 15;

  f32x4 acc[NI][4];
#pragma unroll
  for (int i = 0; i < NI; i++)
#pragma unroll
    for (int j = 0; j < 4; j++) acc[i][j] = (f32x4){0.f, 0.f, 0.f, 0.f};

  const int lrow = lane >> 2;
  const int lcol = (lane & 3) * 8;
  const ushort* gsrc[NC];
  ushort* ldst[NC];
#pragma unroll
  for (int t = 0; t < NC; t++) {
    const int c = w * NC + t;
    if (c < NA) {
      ldst[t] = sa + c * 512;
      gsrc[t] = Ab + (long)(row0 + c * 16 + lrow) * K + lcol;
    } else {
      ldst[t] = sb + (c - NA) * 512;
      gsrc[t] = Bb + (long)(col0 + (c - NA) * 16 + lrow) * K + lcol;
    }
  }

  for (int k0 = 0; k0 < Kend; k0 += 32) {
#pragma unroll
    for (int t = 0; t < NC; t++) async_ld16(gsrc[t] + k0, ldst[t]);
    __syncthreads();
    bf16x8 af[NI], bfr[4];
#pragma unroll
    for (int i = 0; i < NI; i++)
      af[i] = *(const bf16x8*)(sa + (wr * (TM / 2) + i * 16 + l16) * 32 + quad * 8);
#pragma unroll
    for (int j = 0; j < 4; j++)
      bfr[j] = *(const bf16x8*)(sb + (wc * 64 + j * 16 + l16) * 32 + quad * 8);
#pragma unroll
    for (int i = 0; i < NI; i++)
#pragma unroll
      for (int j = 0; j < 4; j++)
        acc[i][j] = __builtin_amdgcn_mfma_f32_16x16x32_bf16(af[i], bfr[j], acc[i][j], 0, 0, 0);
    __syncthreads();
  }

#pragma unroll
  for (int i = 0; i < NI; i++) {
    const int rb = row0 + wr * (TM / 2) + i * 16 + quad * 4;
#pragma unroll
    for (int j = 0; j < 4; j++) {
      const int c = col0 + wc * 64 + j * 16 + l16;
#pragma unroll
      for (int r = 0; r < 4; r++) {
        float v = acc[i][j][r] * scale;
        long off = (long)bz * sC + (long)(rb + r) * N + c;
        if (OUT_BF16)
          ((ushort*)Cv)[off] = f2bf(v);
        else
          ((float*)Cv)[off] = v;
      }
    }
  }
}

// ---------------------------------------------------------------------------
// 256x256 4-phase GEMM, derived-waits pipeline (T2 swizzle + T3/T4 counted
// vmcnt + T5 setprio). BK=64, 8 waves (2M x 4N), wave tile 128x64, 128 KiB
// double-buffered LDS.
// LDS layout per buffer/operand: [256 rows][64 k] bf16 with ushort-index
// XOR swizzle idx = row*64 + (col ^ ((row&7)<<3)); realized as linear
// global_load_lds dest + inverse-swizzled global SOURCE + swizzled ds_read
// (rule #21: both-sides-or-neither).
// Staging rounds match phase consumption (2 loads/thread each):
//   R0 = A rows {0-63,128-191}   (MQ=0 set, consumed by phases 0,1)
//   R1 = B rows {0-31,64-95,128-159,192-223} (NQ=0: phases 0,2)
//   R2 = B rows +32              (NQ=1: phases 1,3)
//   R3 = A rows {64-127,192-255} (MQ=1: phases 2,3)
// Issue for tile t+1: R0+R1 @p0, R2 @p1, R3 @p2. Waits validate ONE PHASE
// AHEAD: vmcnt(6) @p0 (validates R2), vmcnt(6) @p1 (R3), none @p2,
// vmcnt(4) @p3 (next tile's R0,R1). Every load has >=3 phases (~600+ cyc)
// of latency cover; vmcnt(0) never in steady state.
// MASKMODE 2: truncate K to the gates' nonzero range (64-granular).
template <int MASKMODE, bool OUT_BF16>
__global__ __launch_bounds__(512, 2) void gemm256(const ushort* __restrict__ A,
                                                  const ushort* __restrict__ Bt,
                                                  void* __restrict__ Cv, int N, int K,
                                                  long sA, long sB, long sC, float scale) {
  __shared__ __align__(16) ushort lds[2][2][256 * 64];  // [buf][A/B] 128 KiB
  const int bz = blockIdx.z;
  const int row0 = blockIdx.y * 256;
  const int col0 = blockIdx.x * 256;
  int Kend = K;
  if (MASKMODE == 2) {
    int kl = ((row0 + 255) >> 2) + 1;
    Kend = min(K, (kl + 63) & ~63);
  }
  const int NT = Kend >> 6;
  const ushort* Ab = A + (long)bz * sA;
  const ushort* Bb = Bt + (long)bz * sB;

  const int tid = threadIdx.x;
  const int w = tid >> 6, lane = tid & 63;
  const int wr = w >> 2, wc = w & 3;  // 2 x 4 wave grid
  const int quad = lane >> 4, l16 = lane & 15;

  f32x4 acc[8][4];
#pragma unroll
  for (int i = 0; i < 8; i++)
#pragma unroll
    for (int j = 0; j < 4; j++) acc[i][j] = (f32x4){0.f, 0.f, 0.f, 0.f};

  // staging addresses. Each wave-load covers 8 consecutive rows starting at a
  // multiple of 8; lane l -> row base+(l>>3), LDS linear col (l&7)*8 with
  // global col pre-swizzled by the row's low-3-bits: ((l&7)^(l>>3))*8.
  const int lrow = lane >> 3;
  const int lcol = ((lane & 7) ^ lrow) << 3;
  const int bwA = w * 8;                             // A wave row base
  const int bwB = ((w >> 2) << 6) + ((w & 3) << 3);  // B wave row base (NQ0 set)

  const ushort* a00 = Ab + (long)(row0 + bwA + lrow) * K + lcol;        // rows  0- 63
  const ushort* a01 = a00 + (long)128 * K;                              // rows 128-191
  const ushort* a30 = a00 + (long)64 * K;                               // rows  64-127
  const ushort* a31 = a00 + (long)192 * K;                              // rows 192-255
  const ushort* b10 = Bb + (long)(col0 + bwB + lrow) * K + lcol;        // NQ0 lo
  const ushort* b11 = b10 + (long)128 * K;                              // NQ0 hi
  const ushort* b20 = b10 + (long)32 * K;                               // NQ1 lo
  const ushort* b21 = b10 + (long)160 * K;                              // NQ1 hi

  const uint dA00 = (uint)(bwA)*64, dA01 = (uint)(bwA + 128) * 64;
  const uint dA30 = (uint)(bwA + 64) * 64, dA31 = (uint)(bwA + 192) * 64;
  const uint dB10 = (uint)(bwB)*64, dB11 = (uint)(bwB + 128) * 64;
  const uint dB20 = (uint)(bwB + 32) * 64, dB21 = (uint)(bwB + 160) * 64;

#define STG_R0(nb, kk)                                    \
  do {                                                    \
    async_ld16(a00 + (kk), &lds[nb][0][dA00]);            \
    async_ld16(a01 + (kk), &lds[nb][0][dA01]);            \
  } while (0)
#define STG_R1(nb, kk)                                    \
  do {                                                    \
    async_ld16(b10 + (kk), &lds[nb][1][dB10]);            \
    async_ld16(b11 + (kk), &lds[nb][1][dB11]);            \
  } while (0)
#define STG_R2(nb, kk)                                    \
  do {                                                    \
    async_ld16(b20 + (kk), &lds[nb][1][dB20]);            \
    async_ld16(b21 + (kk), &lds[nb][1][dB21]);            \
  } while (0)
#define STG_R3(nb, kk)                                    \
  do {                                                    \
    async_ld16(a30 + (kk), &lds[nb][0][dA30]);            \
    async_ld16(a31 + (kk), &lds[nb][0][dA31]);            \
  } while (0)

#define LDA_(MQ)                                                            \
  _Pragma("unroll") for (int m = 0; m < 4; m++) _Pragma("unroll")           \
  for (int ks = 0; ks < 2; ks++) {                                          \
    const int row = wr * 128 + (MQ)*64 + m * 16 + l16;                      \
    af[m][ks] = *(const bf16x8*)&lds[cbuf][0]                               \
        [row * 64 + ((ks * 32 + quad * 8) ^ ((l16 & 7) << 3))];             \
  }
#define LDB_(NQ)                                                            \
  _Pragma("unroll") for (int n = 0; n < 2; n++) _Pragma("unroll")           \
  for (int ks = 0; ks < 2; ks++) {                                          \
    const int row = wc * 64 + (NQ)*32 + n * 16 + l16;                       \
    bv[n][ks] = *(const bf16x8*)&lds[cbuf][1]                               \
        [row * 64 + ((ks * 32 + quad * 8) ^ ((l16 & 7) << 3))];             \
  }
#define MM_(MQ, NQ)                                                         \
  __builtin_amdgcn_s_setprio(1);                                            \
  _Pragma("unroll") for (int m = 0; m < 4; m++) _Pragma("unroll")           \
  for (int n = 0; n < 2; n++) _Pragma("unroll")                             \
  for (int ks = 0; ks < 2; ks++)                                            \
    acc[(MQ)*4 + m][(NQ)*2 + n] = __builtin_amdgcn_mfma_f32_16x16x32_bf16(  \
        af[m][ks], bv[n][ks], acc[(MQ)*4 + m][(NQ)*2 + n], 0, 0, 0);        \
  __builtin_amdgcn_s_setprio(0);
#define VMC(n) asm volatile("s_waitcnt vmcnt(" #n ")" ::: "memory")
#define SCB __builtin_amdgcn_sched_barrier(0)
#define BAR __builtin_amdgcn_s_barrier()

  // prologue: stage K-tile 0 into buffer 0; wait for R0,R1 only (R2,R3 in flight)
  STG_R0(0, 0);
  STG_R1(0, 0);
  STG_R2(0, 0);
  STG_R3(0, 0);
  VMC(4);
  SCB;
  BAR;

  for (int t = 0; t < NT; ++t) {
    const int cbuf = t & 1;
    const int nb = cbuf ^ 1;
    const int kn = (t + 1) << 6;
    const bool more = (t + 1 < NT);
    {  // phase 0: compute (0,0); needs R0,R1 (validated last iter p3)
      bf16x8 af[4][2], bv[2][2];
      LDA_(0)
      LDB_(0)
      if (more) {
        STG_R0(nb, kn);
        STG_R1(nb, kn);
        VMC(6);  // cur R2 landed (for p1); 6 in flight: cur R3 + next R0,R1
      } else {
        VMC(2);  // cur R2 landed; cur R3 still in flight
      }
      SCB;
      BAR;
      MM_(0, 0)
      BAR;
    }
    {  // phase 1: compute (0,1); needs R2 (validated p0)
      bf16x8 af[4][2], bv[2][2];
      LDA_(0)
      LDB_(1)
      if (more) {
        STG_R2(nb, kn);
        VMC(6);  // cur R3 landed (for p2); 6 in flight: next R0,R1,R2
      } else {
        VMC(0);  // cur R3 landed
      }
      SCB;
      BAR;
      MM_(0, 1)
      BAR;
    }
    {  // phase 2: compute (1,0); needs R3 (validated p1). no wait.
      bf16x8 af[4][2], bv[2][2];
      LDA_(1)
      LDB_(0)
      if (more) STG_R3(nb, kn);
      BAR;
      MM_(1, 0)
      BAR;
    }
    {  // phase 3: compute (1,1); nothing new. validate next tile's R0,R1.
      bf16x8 af[4][2], bv[2][2];
      LDA_(1)
      LDB_(1)
      if (more) {
        VMC(4);  // next R0,R1 landed (for next p0); next R2,R3 in flight
        SCB;
      }
      BAR;
      MM_(1, 1)
      BAR;
    }
  }
#undef STG_R0
#undef STG_R1
#undef STG_R2
#undef STG_R3
#undef LDA_
#undef LDB_
#undef MM_
#undef VMC
#undef SCB
#undef BAR

#pragma unroll
  for (int i = 0; i < 8; i++) {
    const int rb = row0 + wr * 128 + (i >> 2) * 64 + (i & 3) * 16 + quad * 4;
#pragma unroll
    for (int j = 0; j < 4; j++) {
      const int cc = col0 + wc * 64 + (j >> 1) * 32 + (j & 1) * 16 + l16;
#pragma unroll
      for (int r = 0; r < 4; r++) {
        float v = acc[i][j][r] * scale;
        long off = (long)bz * sC + (long)(rb + r) * N + cc;
        if (OUT_BF16)
          ((ushort*)Cv)[off] = f2bf(v);
        else
          ((float*)Cv)[off] = v;
      }
    }
  }
}

// one WAVE per (b,t) row: current-score dot + masked softmax over 513.
__global__ __launch_bounds__(256) void softmax_gate(const ushort* __restrict__ u_bf,
                                                    const float* __restrict__ m_cur,
                                                    const float* __restrict__ scores,
                                                    float* __restrict__ out_gc,
                                                    float* __restrict__ out_attn,
                                                    ushort* __restrict__ gates_bf) {
  const int wv = threadIdx.x >> 6, lane = threadIdx.x & 63;
  const int bt = blockIdx.x * 4 + wv;
  const int t = bt & (T_SZ - 1);
  const ushort* urow = u_bf + (long)bt * D_MODEL;
  const float* mrow = m_cur + (long)bt * D_MODEL;

  float part = 0.f;
#pragma unroll
  for (int c = 0; c < 4; c++) {
    uint4 uv = *(const uint4*)(urow + c * 512 + lane * 8);
    float4 m0 = *(const float4*)(mrow + c * 512 + lane * 8);
    float4 m1 = *(const float4*)(mrow + c * 512 + lane * 8 + 4);
    part += bflo(uv.x) * m0.x + bfhi(uv.x) * m0.y + bflo(uv.y) * m0.z + bfhi(uv.y) * m0.w +
            bflo(uv.z) * m1.x + bfhi(uv.z) * m1.y + bflo(uv.w) * m1.z + bfhi(uv.w) * m1.w;
  }
#pragma unroll
  for (int m = 32; m; m >>= 1) part += __shfl_xor(part, m, 64);
  const float curs = part * 0.022097086912079608f;  // 1/sqrt(2048)

  const int nmax = t >> 2;
  const float* srow = scores + (long)bt * N_SZ;
  float sc[8];
  float lmax = curs;
#pragma unroll
  for (int k = 0; k < 8; k++) {
    const int n = k * 64 + lane;
    sc[k] = srow[n];
    if (n <= nmax) lmax = fmaxf(lmax, sc[k]);
  }
#pragma unroll
  for (int m = 32; m; m >>= 1) lmax = fmaxf(lmax, __shfl_xor(lmax, m, 64));

  float lsum = (lane == 0) ? __expf(curs - lmax) : 0.f;
#pragma unroll
  for (int k = 0; k < 8; k++) {
    const int n = k * 64 + lane;
    sc[k] = (n <= nmax) ? __expf(sc[k] - lmax) : 0.f;
    lsum += sc[k];
  }
#pragma unroll
  for (int m = 32; m; m >>= 1) lsum += __shfl_xor(lsum, m, 64);
  const float inv = 1.f / lsum;

  float* arow = out_attn + (long)bt * (N_SZ + 1);
  ushort* grow = gates_bf + (long)bt * N_SZ;
#pragma unroll
  for (int k = 0; k < 8; k++) {
    const int n = k * 64 + lane;
    const float wgt = sc[k] * inv;
    arow[n] = wgt;
    grow[n] = f2bf(wgt);
  }
  if (lane == 0) {
    const float g = __expf(curs - lmax) * inv;
    arow[N_SZ] = g;
    out_gc[bt] = g;
  }
}

extern "C" void kernel_launch(void* const* d_in, const int* in_sizes, int n_in,
                              void* d_out, int out_size, void* d_ws, size_t ws_size,
                              hipStream_t stream) {
  const float* x = (const float*)d_in[0];        // (B,T,D) fp32
  const float* h_stack = (const float*)d_in[1];  // (B,N,D) fp32
  const float* m_stack = (const float*)d_in[2];  // (B,N,D) fp32
  const float* m_cur = (const float*)d_in[3];    // (B,T,D) fp32
  const float* W = (const float*)d_in[5];        // (D,D) fp32  (d_in[4] = mask, recomputed)

  float* out = (float*)d_out;  // fp32 = reference output dtype
  float* out_h = out;                                 // (B,T,D)
  float* out_gc = out + (long)B_SZ * T_SZ * D_MODEL;  // (B,T,1)
  float* out_attn = out_gc + B_SZ * T_SZ;             // (B,T,N+1)

  // workspace layout (112 MB total)
  char* ws = (char*)d_ws;
  ushort* x_bf = (ushort*)ws;               // B*T*D   = 16,777,216
  ushort* u_bf = x_bf + 16777216;           // B*T*D
  ushort* W_bf = u_bf + 16777216;           // D*D     =  4,194,304
  ushort* ms_bf = W_bf + 4194304;           // B*N*D
  ushort* gates = ms_bf + 4194304;          // B*T*N   =  4,194,304
  ushort* hsT = gates + 4194304;            // B*D*N
  float* scores = (float*)(hsT + 4194304);  // B*T*N fp32

  conv_all<<<12288, 256, 0, stream>>>(x, W, m_stack, x_bf, W_bf, ms_bf);
  transpose_conv<<<dim3(N_SZ / 32, D_MODEL / 32, B_SZ), dim3(32, 8), 0, stream>>>(h_stack, hsT);

  // u = x @ W^T  (M=8192, N=2048, K=2048), out bf16. 256 blocks = 1/CU.
  gemm256<0, true><<<dim3(D_MODEL / 256, (B_SZ * T_SZ) / 256, 1), 512, 0, stream>>>(
      x_bf, W_bf, u_bf, D_MODEL, D_MODEL, 0, 0, 0, 1.0f);

  // scores = u @ m_stack^T * scale  per batch (M=2048, N=512, K=2048), fp32 out.
  // stays on the 128-col-tile path: 320 active blocks vs 64 at 256² tiling.
  gemm_bt<64, 1, false><<<dim3(N_SZ / 128, T_SZ / 64, B_SZ), 256, 0, stream>>>(
      u_bf, ms_bf, scores, N_SZ, D_MODEL, (long)T_SZ * D_MODEL, (long)N_SZ * D_MODEL,
      (long)T_SZ * N_SZ, 0.022097086912079608f);

  softmax_gate<<<(B_SZ * T_SZ) / 4, 256, 0, stream>>>(u_bf, m_cur, scores, out_gc, out_attn,
                                                      gates);

  // h = gates @ hsT^T  per batch (M=2048, N=2048, K truncated 64..512), fp32 out
  gemm256<2, false><<<dim3(D_MODEL / 256, T_SZ / 256, B_SZ), 512, 0, stream>>>(
      gates, hsT, out_h, D_MODEL, N_SZ, (long)T_SZ * N_SZ, (long)D_MODEL * N_SZ,
      (long)T_SZ * D_MODEL, 1.0f);
}

// Round 5
// 350.031 us; speedup vs baseline: 1.1259x; 1.0348x over previous
//
#include <hip/hip_runtime.h>

#define D_MODEL 2048
#define B_SZ 4
#define T_SZ 2048
#define N_SZ 512

typedef __bf16 bf16x8 __attribute__((ext_vector_type(8)));
typedef float f32x4 __attribute__((ext_vector_type(4)));
typedef ushort u16x8 __attribute__((ext_vector_type(8)));

// fp32 -> bf16 round-to-nearest-even
__device__ __forceinline__ ushort f2bf(float f) {
  unsigned u = __float_as_uint(f);
  unsigned r = (u + 0x7fffu + ((u >> 16) & 1u)) >> 16;
  return (ushort)r;
}
__device__ __forceinline__ float bflo(unsigned w) { return __uint_as_float(w << 16); }
__device__ __forceinline__ float bfhi(unsigned w) { return __uint_as_float(w & 0xffff0000u); }

__device__ __forceinline__ void async_ld16(const ushort* g, ushort* l) {
  __builtin_amdgcn_global_load_lds(
      (const __attribute__((address_space(1))) void*)g,
      (__attribute__((address_space(3))) void*)l, 16, 0, 0);
}

// single fused fp32->bf16 conversion for x (8192 blk), W (2048 blk), m_stack (2048 blk)
__global__ __launch_bounds__(256) void conv_all(const float* __restrict__ x,
                                                const float* __restrict__ W,
                                                const float* __restrict__ ms,
                                                ushort* __restrict__ x_bf,
                                                ushort* __restrict__ W_bf,
                                                ushort* __restrict__ ms_bf) {
  const int bid = blockIdx.x;
  const float* src;
  ushort* dst;
  long blk;
  if (bid < 8192) { src = x; dst = x_bf; blk = bid; }
  else if (bid < 10240) { src = W; dst = W_bf; blk = bid - 8192; }
  else { src = ms; dst = ms_bf; blk = bid - 10240; }
  const long i = (blk * 256 + threadIdx.x) * 8;
  float4 a = *(const float4*)(src + i);
  float4 b = *(const float4*)(src + i + 4);
  u16x8 o;
  o[0] = f2bf(a.x); o[1] = f2bf(a.y); o[2] = f2bf(a.z); o[3] = f2bf(a.w);
  o[4] = f2bf(b.x); o[5] = f2bf(b.y); o[6] = f2bf(b.z); o[7] = f2bf(b.w);
  *(u16x8*)(dst + i) = o;
}

// h_stack (B,N,D) fp32 -> hsT (B,D,N) bf16
__global__ __launch_bounds__(256) void transpose_conv(const float* __restrict__ src,
                                                      ushort* __restrict__ dst) {
  __shared__ ushort tile[32][33];
  const int b = blockIdx.z;
  const int n0 = blockIdx.x * 32, d0 = blockIdx.y * 32;
  const int tx = threadIdx.x, ty = threadIdx.y;  // (32,8)
  const float* s = src + (long)b * N_SZ * D_MODEL;
  ushort* d = dst + (long)b * D_MODEL * N_SZ;
#pragma unroll
  for (int r = 0; r < 4; r++)
    tile[ty + r * 8][tx] = f2bf(s[(long)(n0 + ty + r * 8) * D_MODEL + d0 + tx]);
  __syncthreads();
#pragma unroll
  for (int r = 0; r < 4; r++)
    d[(long)(d0 + ty + r * 8) * N_SZ + n0 + tx] = tile[tx][ty + r * 8];
}

// ---------------------------------------------------------------------------
// legacy 128-col tile GEMM — kept for the scores GEMM (N=512 -> needs the
// finer grid for CU coverage). C[M,N] = A[M,K] * Bt[N,K]^T, bf16 in.
// MASKMODE 1: skip tile if col0 > (t_max>>2).
template <int TM, int MASKMODE, bool OUT_BF16>
__global__ __launch_bounds__(256) void gemm_bt(const ushort* __restrict__ A,
                                               const ushort* __restrict__ Bt,
                                               void* __restrict__ Cv, int N, int K,
                                               long sA, long sB, long sC, float scale) {
  constexpr int NA = TM / 16;   // A-tile 1KB chunks
  constexpr int NCH = NA + 8;   // total chunks (B-tile has 8)
  constexpr int NC = NCH / 4;   // chunks per wave
  constexpr int NI = TM / 32;   // i-blocks per wave
  __shared__ __align__(16) ushort sa[TM * 32];
  __shared__ __align__(16) ushort sb[128 * 32];
  const int bz = blockIdx.z;
  const int row0 = blockIdx.y * TM;
  const int col0 = blockIdx.x * 128;
  if (MASKMODE == 1 && col0 > ((row0 + TM - 1) >> 2)) return;
  int Kend = K;
  if (MASKMODE == 2) {
    int kl = ((row0 + TM - 1) >> 2) + 1;
    Kend = min(K, (kl + 31) & ~31);
  }
  const ushort* Ab = A + (long)bz * sA;
  const ushort* Bb = Bt + (long)bz * sB;

  const int tid = threadIdx.x;
  const int w = tid >> 6, lane = tid & 63;
  const int wr = w >> 1, wc = w & 1;
  const int quad = lane >> 4, l16 = lane & 15;

  f32x4 acc[NI][4];
#pragma unroll
  for (int i = 0; i < NI; i++)
#pragma unroll
    for (int j = 0; j < 4; j++) acc[i][j] = (f32x4){0.f, 0.f, 0.f, 0.f};

  const int lrow = lane >> 2;
  const int lcol = (lane & 3) * 8;
  const ushort* gsrc[NC];
  ushort* ldst[NC];
#pragma unroll
  for (int t = 0; t < NC; t++) {
    const int c = w * NC + t;
    if (c < NA) {
      ldst[t] = sa + c * 512;
      gsrc[t] = Ab + (long)(row0 + c * 16 + lrow) * K + lcol;
    } else {
      ldst[t] = sb + (c - NA) * 512;
      gsrc[t] = Bb + (long)(col0 + (c - NA) * 16 + lrow) * K + lcol;
    }
  }

  for (int k0 = 0; k0 < Kend; k0 += 32) {
#pragma unroll
    for (int t = 0; t < NC; t++) async_ld16(gsrc[t] + k0, ldst[t]);
    __syncthreads();
    bf16x8 af[NI], bfr[4];
#pragma unroll
    for (int i = 0; i < NI; i++)
      af[i] = *(const bf16x8*)(sa + (wr * (TM / 2) + i * 16 + l16) * 32 + quad * 8);
#pragma unroll
    for (int j = 0; j < 4; j++)
      bfr[j] = *(const bf16x8*)(sb + (wc * 64 + j * 16 + l16) * 32 + quad * 8);
#pragma unroll
    for (int i = 0; i < NI; i++)
#pragma unroll
      for (int j = 0; j < 4; j++)
        acc[i][j] = __builtin_amdgcn_mfma_f32_16x16x32_bf16(af[i], bfr[j], acc[i][j], 0, 0, 0);
    __syncthreads();
  }

#pragma unroll
  for (int i = 0; i < NI; i++) {
    const int rb = row0 + wr * (TM / 2) + i * 16 + quad * 4;
#pragma unroll
    for (int j = 0; j < 4; j++) {
      const int c = col0 + wc * 64 + j * 16 + l16;
#pragma unroll
      for (int r = 0; r < 4; r++) {
        float v = acc[i][j][r] * scale;
        long off = (long)bz * sC + (long)(rb + r) * N + c;
        if (OUT_BF16)
          ((ushort*)Cv)[off] = f2bf(v);
        else
          ((float*)Cv)[off] = v;
      }
    }
  }
}

// ---------------------------------------------------------------------------
// 256x256 4-phase GEMM, single-read fragments (T2 swizzle + T3/T4 counted
// vmcnt + T5 setprio). BK=64, 8 waves (2M x 4N), wave tile 128x64, 128 KiB
// double-buffered LDS.
// LDS layout per buffer/operand: [256 rows][64 k] bf16 with ushort-index
// XOR swizzle idx = row*64 + (col ^ ((row&7)<<3)); realized as linear
// global_load_lds dest + inverse-swizzled global SOURCE + swizzled ds_read
// (rule #21: both-sides-or-neither).
// LDS-BW note (R4 post-mortem): reading each fragment once is the lever.
// B-frags (8 b128 = 32 VGPR) are read at phase 0 and HELD for the whole
// K-tile; each phase reads one A m-pair (4 b128) and runs 16 MFMA.
// 24 b128/wave/K-tile (vs 48 with quadrant re-reads) -> 192 KiB/CU/K-tile.
// Staging rounds (2 loads/thread each):
//   R0 = A rows {0-63,128-191}   (A m-pairs 0,1 of both wr)
//   R1 = B rows {0-31,64-95,128-159,192-223}
//   R2 = B rows +32
//   R3 = A rows {64-127,192-255} (A m-pairs 2,3)
// Issue for tile t+1: R0+R1 @p0, R2 @p1, R3 @p2. Waits: vmcnt(4) @p0
// (validates cur R3 before p2), vmcnt(2) @p3 (validates next R0,R1,R2
// before next p0). vmcnt(0) never in steady state.
// MASKMODE 2: truncate K to the gates' nonzero range (64-granular).
template <int MASKMODE, bool OUT_BF16>
__global__ __launch_bounds__(512, 2) void gemm256(const ushort* __restrict__ A,
                                                  const ushort* __restrict__ Bt,
                                                  void* __restrict__ Cv, int N, int K,
                                                  long sA, long sB, long sC, float scale) {
  __shared__ __align__(16) ushort lds[2][2][256 * 64];  // [buf][A/B] 128 KiB
  const int bz = blockIdx.z;
  const int row0 = blockIdx.y * 256;
  const int col0 = blockIdx.x * 256;
  int Kend = K;
  if (MASKMODE == 2) {
    int kl = ((row0 + 255) >> 2) + 1;
    Kend = min(K, (kl + 63) & ~63);
  }
  const int NT = Kend >> 6;
  const ushort* Ab = A + (long)bz * sA;
  const ushort* Bb = Bt + (long)bz * sB;

  const int tid = threadIdx.x;
  const int w = tid >> 6, lane = tid & 63;
  const int wr = w >> 2, wc = w & 3;  // 2 x 4 wave grid
  const int quad = lane >> 4, l16 = lane & 15;

  f32x4 acc[8][4];
#pragma unroll
  for (int i = 0; i < 8; i++)
#pragma unroll
    for (int j = 0; j < 4; j++) acc[i][j] = (f32x4){0.f, 0.f, 0.f, 0.f};

  // staging addresses. Each wave-load covers 8 consecutive rows starting at a
  // multiple of 8; lane l -> row base+(l>>3), LDS linear col (l&7)*8 with
  // global col pre-swizzled by the row's low-3-bits: ((l&7)^(l>>3))*8.
  const int lrow = lane >> 3;
  const int lcol = ((lane & 7) ^ lrow) << 3;
  const int bwA = w * 8;                             // A wave row base
  const int bwB = ((w >> 2) << 6) + ((w & 3) << 3);  // B wave row base (R1 set)

  const ushort* a00 = Ab + (long)(row0 + bwA + lrow) * K + lcol;  // rows  0- 63
  const ushort* a01 = a00 + (long)128 * K;                        // rows 128-191
  const ushort* a30 = a00 + (long)64 * K;                         // rows  64-127
  const ushort* a31 = a00 + (long)192 * K;                        // rows 192-255
  const ushort* b10 = Bb + (long)(col0 + bwB + lrow) * K + lcol;  // R1 lo
  const ushort* b11 = b10 + (long)128 * K;                        // R1 hi
  const ushort* b20 = b10 + (long)32 * K;                         // R2 lo
  const ushort* b21 = b10 + (long)160 * K;                        // R2 hi

  const uint dA00 = (uint)(bwA)*64, dA01 = (uint)(bwA + 128) * 64;
  const uint dA30 = (uint)(bwA + 64) * 64, dA31 = (uint)(bwA + 192) * 64;
  const uint dB10 = (uint)(bwB)*64, dB11 = (uint)(bwB + 128) * 64;
  const uint dB20 = (uint)(bwB + 32) * 64, dB21 = (uint)(bwB + 160) * 64;

#define STG_R0(nb, kk)                         \
  do {                                         \
    async_ld16(a00 + (kk), &lds[nb][0][dA00]); \
    async_ld16(a01 + (kk), &lds[nb][0][dA01]); \
  } while (0)
#define STG_R1(nb, kk)                         \
  do {                                         \
    async_ld16(b10 + (kk), &lds[nb][1][dB10]); \
    async_ld16(b11 + (kk), &lds[nb][1][dB11]); \
  } while (0)
#define STG_R2(nb, kk)                         \
  do {                                         \
    async_ld16(b20 + (kk), &lds[nb][1][dB20]); \
    async_ld16(b21 + (kk), &lds[nb][1][dB21]); \
  } while (0)
#define STG_R3(nb, kk)                         \
  do {                                         \
    async_ld16(a30 + (kk), &lds[nb][0][dA30]); \
    async_ld16(a31 + (kk), &lds[nb][0][dA31]); \
  } while (0)

// read A m-pair P (m-frags 2P, 2P+1; rows wr*128 + mf*16), 4 b128
#define LDA_PAIR(P)                                                 \
  _Pragma("unroll") for (int mi = 0; mi < 2; mi++) _Pragma("unroll") \
  for (int ks = 0; ks < 2; ks++) {                                  \
    const int row = wr * 128 + ((P)*2 + mi) * 16 + l16;             \
    af[mi][ks] = *(const bf16x8*)&lds[cbuf][0]                      \
        [row * 64 + ((ks * 32 + quad * 8) ^ ((l16 & 7) << 3))];     \
  }
// read ALL B n-frags (rows wc*64 + n*16), 8 b128, held for the K-tile
#define LDB_ALL                                                     \
  _Pragma("unroll") for (int n = 0; n < 4; n++) _Pragma("unroll")   \
  for (int ks = 0; ks < 2; ks++) {                                  \
    const int row = wc * 64 + n * 16 + l16;                         \
    bv[n][ks] = *(const bf16x8*)&lds[cbuf][1]                       \
        [row * 64 + ((ks * 32 + quad * 8) ^ ((l16 & 7) << 3))];     \
  }
#define MM_PAIR(P)                                                            \
  __builtin_amdgcn_s_setprio(1);                                              \
  _Pragma("unroll") for (int mi = 0; mi < 2; mi++) _Pragma("unroll")          \
  for (int n = 0; n < 4; n++) _Pragma("unroll")                               \
  for (int ks = 0; ks < 2; ks++)                                              \
    acc[(P)*2 + mi][n] = __builtin_amdgcn_mfma_f32_16x16x32_bf16(             \
        af[mi][ks], bv[n][ks], acc[(P)*2 + mi][n], 0, 0, 0);                  \
  __builtin_amdgcn_s_setprio(0);
#define VMC(n) asm volatile("s_waitcnt vmcnt(" #n ")" ::: "memory")
#define SCB __builtin_amdgcn_sched_barrier(0)
#define BAR __builtin_amdgcn_s_barrier()

  // prologue: stage K-tile 0 into buffer 0; wait for R0,R1,R2 (R3 in flight)
  STG_R0(0, 0);
  STG_R1(0, 0);
  STG_R2(0, 0);
  STG_R3(0, 0);
  VMC(2);
  SCB;
  BAR;

  for (int t = 0; t < NT; ++t) {
    const int cbuf = t & 1;
    const int nb = cbuf ^ 1;
    const int kn = (t + 1) << 6;
    const bool more = (t + 1 < NT);
    bf16x8 bv[4][2];  // B held across the K-tile
    {  // phase 0: B-all + A-pair0; stage next R0,R1; validate cur R3
      bf16x8 af[2][2];
      LDB_ALL
      LDA_PAIR(0)
      if (more) {
        STG_R0(nb, kn);
        STG_R1(nb, kn);
        VMC(4);  // cur R3 landed; next R0,R1 in flight
      } else {
        VMC(0);  // cur R3 landed
      }
      SCB;
      BAR;
      MM_PAIR(0)
      BAR;
    }
    {  // phase 1: A-pair1 (from R0); stage next R2
      bf16x8 af[2][2];
      LDA_PAIR(1)
      if (more) STG_R2(nb, kn);
      BAR;
      MM_PAIR(1)
      BAR;
    }
    {  // phase 2: A-pair2 (from R3, validated @p0); stage next R3
      bf16x8 af[2][2];
      LDA_PAIR(2)
      if (more) STG_R3(nb, kn);
      BAR;
      MM_PAIR(2)
      BAR;
    }
    {  // phase 3: A-pair3; validate next R0,R1,R2 for next p0
      bf16x8 af[2][2];
      LDA_PAIR(3)
      if (more) {
        VMC(2);  // next R0,R1,R2 landed; next R3 in flight
        SCB;
      }
      BAR;
      MM_PAIR(3)
      BAR;
    }
  }
#undef STG_R0
#undef STG_R1
#undef STG_R2
#undef STG_R3
#undef LDA_PAIR
#undef LDB_ALL
#undef MM_PAIR
#undef VMC
#undef SCB
#undef BAR

#pragma unroll
  for (int i = 0; i < 8; i++) {
    const int rb = row0 + wr * 128 + (i >> 2) * 64 + (i & 3) * 16 + quad * 4;
#pragma unroll
    for (int j = 0; j < 4; j++) {
      const int cc = col0 + wc * 64 + (j >> 1) * 32 + (j & 1) * 16 + l16;
#pragma unroll
      for (int r = 0; r < 4; r++) {
        float v = acc[i][j][r] * scale;
        long off = (long)bz * sC + (long)(rb + r) * N + cc;
        if (OUT_BF16)
          ((ushort*)Cv)[off] = f2bf(v);
        else
          ((float*)Cv)[off] = v;
      }
    }
  }
}

// one WAVE per (b,t) row: current-score dot + masked softmax over 513.
__global__ __launch_bounds__(256) void softmax_gate(const ushort* __restrict__ u_bf,
                                                    const float* __restrict__ m_cur,
                                                    const float* __restrict__ scores,
                                                    float* __restrict__ out_gc,
                                                    float* __restrict__ out_attn,
                                                    ushort* __restrict__ gates_bf) {
  const int wv = threadIdx.x >> 6, lane = threadIdx.x & 63;
  const int bt = blockIdx.x * 4 + wv;
  const int t = bt & (T_SZ - 1);
  const ushort* urow = u_bf + (long)bt * D_MODEL;
  const float* mrow = m_cur + (long)bt * D_MODEL;

  float part = 0.f;
#pragma unroll
  for (int c = 0; c < 4; c++) {
    uint4 uv = *(const uint4*)(urow + c * 512 + lane * 8);
    float4 m0 = *(const float4*)(mrow + c * 512 + lane * 8);
    float4 m1 = *(const float4*)(mrow + c * 512 + lane * 8 + 4);
    part += bflo(uv.x) * m0.x + bfhi(uv.x) * m0.y + bflo(uv.y) * m0.z + bfhi(uv.y) * m0.w +
            bflo(uv.z) * m1.x + bfhi(uv.z) * m1.y + bflo(uv.w) * m1.z + bfhi(uv.w) * m1.w;
  }
#pragma unroll
  for (int m = 32; m; m >>= 1) part += __shfl_xor(part, m, 64);
  const float curs = part * 0.022097086912079608f;  // 1/sqrt(2048)

  const int nmax = t >> 2;
  const float* srow = scores + (long)bt * N_SZ;
  float sc[8];
  float lmax = curs;
#pragma unroll
  for (int k = 0; k < 8; k++) {
    const int n = k * 64 + lane;
    sc[k] = srow[n];
    if (n <= nmax) lmax = fmaxf(lmax, sc[k]);
  }
#pragma unroll
  for (int m = 32; m; m >>= 1) lmax = fmaxf(lmax, __shfl_xor(lmax, m, 64));

  float lsum = (lane == 0) ? __expf(curs - lmax) : 0.f;
#pragma unroll
  for (int k = 0; k < 8; k++) {
    const int n = k * 64 + lane;
    sc[k] = (n <= nmax) ? __expf(sc[k] - lmax) : 0.f;
    lsum += sc[k];
  }
#pragma unroll
  for (int m = 32; m; m >>= 1) lsum += __shfl_xor(lsum, m, 64);
  const float inv = 1.f / lsum;

  float* arow = out_attn + (long)bt * (N_SZ + 1);
  ushort* grow = gates_bf + (long)bt * N_SZ;
#pragma unroll
  for (int k = 0; k < 8; k++) {
    const int n = k * 64 + lane;
    const float wgt = sc[k] * inv;
    arow[n] = wgt;
    grow[n] = f2bf(wgt);
  }
  if (lane == 0) {
    const float g = __expf(curs - lmax) * inv;
    arow[N_SZ] = g;
    out_gc[bt] = g;
  }
}

extern "C" void kernel_launch(void* const* d_in, const int* in_sizes, int n_in,
                              void* d_out, int out_size, void* d_ws, size_t ws_size,
                              hipStream_t stream) {
  const float* x = (const float*)d_in[0];        // (B,T,D) fp32
  const float* h_stack = (const float*)d_in[1];  // (B,N,D) fp32
  const float* m_stack = (const float*)d_in[2];  // (B,N,D) fp32
  const float* m_cur = (const float*)d_in[3];    // (B,T,D) fp32
  const float* W = (const float*)d_in[5];        // (D,D) fp32  (d_in[4] = mask, recomputed)

  float* out = (float*)d_out;  // fp32 = reference output dtype
  float* out_h = out;                                 // (B,T,D)
  float* out_gc = out + (long)B_SZ * T_SZ * D_MODEL;  // (B,T,1)
  float* out_attn = out_gc + B_SZ * T_SZ;             // (B,T,N+1)

  // workspace layout (112 MB total)
  char* ws = (char*)d_ws;
  ushort* x_bf = (ushort*)ws;               // B*T*D   = 16,777,216
  ushort* u_bf = x_bf + 16777216;           // B*T*D
  ushort* W_bf = u_bf + 16777216;           // D*D     =  4,194,304
  ushort* ms_bf = W_bf + 4194304;           // B*N*D
  ushort* gates = ms_bf + 4194304;          // B*T*N   =  4,194,304
  ushort* hsT = gates + 4194304;            // B*D*N
  float* scores = (float*)(hsT + 4194304);  // B*T*N fp32

  conv_all<<<12288, 256, 0, stream>>>(x, W, m_stack, x_bf, W_bf, ms_bf);
  transpose_conv<<<dim3(N_SZ / 32, D_MODEL / 32, B_SZ), dim3(32, 8), 0, stream>>>(h_stack, hsT);

  // u = x @ W^T  (M=8192, N=2048, K=2048), out bf16. 256 blocks = 1/CU.
  gemm256<0, true><<<dim3(D_MODEL / 256, (B_SZ * T_SZ) / 256, 1), 512, 0, stream>>>(
      x_bf, W_bf, u_bf, D_MODEL, D_MODEL, 0, 0, 0, 1.0f);

  // scores = u @ m_stack^T * scale  per batch (M=2048, N=512, K=2048), fp32 out.
  // stays on the 128-col-tile path: 320 active blocks vs 64 at 256² tiling.
  gemm_bt<64, 1, false><<<dim3(N_SZ / 128, T_SZ / 64, B_SZ), 256, 0, stream>>>(
      u_bf, ms_bf, scores, N_SZ, D_MODEL, (long)T_SZ * D_MODEL, (long)N_SZ * D_MODEL,
      (long)T_SZ * N_SZ, 0.022097086912079608f);

  softmax_gate<<<(B_SZ * T_SZ) / 4, 256, 0, stream>>>(u_bf, m_cur, scores, out_gc, out_attn,
                                                      gates);

  // h = gates @ hsT^T  per batch (M=2048, N=2048, K truncated 64..512), fp32 out
  gemm256<2, false><<<dim3(D_MODEL / 256, T_SZ / 256, B_SZ), 512, 0, stream>>>(
      gates, hsT, out_h, D_MODEL, N_SZ, (long)T_SZ * N_SZ, (long)D_MODEL * N_SZ,
      (long)T_SZ * D_MODEL, 1.0f);
}

// Round 7
// 349.128 us; speedup vs baseline: 1.1288x; 1.0026x over previous
//
#include <hip/hip_runtime.h>

#define D_MODEL 2048
#define B_SZ 4
#define T_SZ 2048
#define N_SZ 512

typedef __bf16 bf16x8 __attribute__((ext_vector_type(8)));
typedef float f32x4 __attribute__((ext_vector_type(4)));
typedef ushort u16x8 __attribute__((ext_vector_type(8)));

// fp32 -> bf16 round-to-nearest-even
__device__ __forceinline__ ushort f2bf(float f) {
  unsigned u = __float_as_uint(f);
  unsigned r = (u + 0x7fffu + ((u >> 16) & 1u)) >> 16;
  return (ushort)r;
}
__device__ __forceinline__ float bflo(unsigned w) { return __uint_as_float(w << 16); }
__device__ __forceinline__ float bfhi(unsigned w) { return __uint_as_float(w & 0xffff0000u); }

__device__ __forceinline__ void async_ld16(const ushort* g, ushort* l) {
  __builtin_amdgcn_global_load_lds(
      (const __attribute__((address_space(1))) void*)g,
      (__attribute__((address_space(3))) void*)l, 16, 0, 0);
}

// single fused fp32->bf16 conversion for x (8192 blk), W (2048 blk), m_stack (2048 blk)
__global__ __launch_bounds__(256) void conv_all(const float* __restrict__ x,
                                                const float* __restrict__ W,
                                                const float* __restrict__ ms,
                                                ushort* __restrict__ x_bf,
                                                ushort* __restrict__ W_bf,
                                                ushort* __restrict__ ms_bf) {
  const int bid = blockIdx.x;
  const float* src;
  ushort* dst;
  long blk;
  if (bid < 8192) { src = x; dst = x_bf; blk = bid; }
  else if (bid < 10240) { src = W; dst = W_bf; blk = bid - 8192; }
  else { src = ms; dst = ms_bf; blk = bid - 10240; }
  const long i = (blk * 256 + threadIdx.x) * 8;
  float4 a = *(const float4*)(src + i);
  float4 b = *(const float4*)(src + i + 4);
  u16x8 o;
  o[0] = f2bf(a.x); o[1] = f2bf(a.y); o[2] = f2bf(a.z); o[3] = f2bf(a.w);
  o[4] = f2bf(b.x); o[5] = f2bf(b.y); o[6] = f2bf(b.z); o[7] = f2bf(b.w);
  *(u16x8*)(dst + i) = o;
}

// h_stack (B,N,D) fp32 -> hsT (B,D,N) bf16
__global__ __launch_bounds__(256) void transpose_conv(const float* __restrict__ src,
                                                      ushort* __restrict__ dst) {
  __shared__ ushort tile[32][33];
  const int b = blockIdx.z;
  const int n0 = blockIdx.x * 32, d0 = blockIdx.y * 32;
  const int tx = threadIdx.x, ty = threadIdx.y;  // (32,8)
  const float* s = src + (long)b * N_SZ * D_MODEL;
  ushort* d = dst + (long)b * D_MODEL * N_SZ;
#pragma unroll
  for (int r = 0; r < 4; r++)
    tile[ty + r * 8][tx] = f2bf(s[(long)(n0 + ty + r * 8) * D_MODEL + d0 + tx]);
  __syncthreads();
#pragma unroll
  for (int r = 0; r < 4; r++)
    d[(long)(d0 + ty + r * 8) * N_SZ + n0 + tx] = tile[tx][ty + r * 8];
}

// ---------------------------------------------------------------------------
// legacy 128-col tile GEMM — kept for the scores GEMM (N=512 -> needs the
// finer grid for CU coverage). C[M,N] = A[M,K] * Bt[N,K]^T, bf16 in.
// MASKMODE 1: skip tile if col0 > (t_max>>2).
template <int TM, int MASKMODE, bool OUT_BF16>
__global__ __launch_bounds__(256) void gemm_bt(const ushort* __restrict__ A,
                                               const ushort* __restrict__ Bt,
                                               void* __restrict__ Cv, int N, int K,
                                               long sA, long sB, long sC, float scale) {
  constexpr int NA = TM / 16;   // A-tile 1KB chunks
  constexpr int NCH = NA + 8;   // total chunks (B-tile has 8)
  constexpr int NC = NCH / 4;   // chunks per wave
  constexpr int NI = TM / 32;   // i-blocks per wave
  __shared__ __align__(16) ushort sa[TM * 32];
  __shared__ __align__(16) ushort sb[128 * 32];
  const int bz = blockIdx.z;
  const int row0 = blockIdx.y * TM;
  const int col0 = blockIdx.x * 128;
  if (MASKMODE == 1 && col0 > ((row0 + TM - 1) >> 2)) return;
  int Kend = K;
  if (MASKMODE == 2) {
    int kl = ((row0 + TM - 1) >> 2) + 1;
    Kend = min(K, (kl + 31) & ~31);
  }
  const ushort* Ab = A + (long)bz * sA;
  const ushort* Bb = Bt + (long)bz * sB;

  const int tid = threadIdx.x;
  const int w = tid >> 6, lane = tid & 63;
  const int wr = w >> 1, wc = w & 1;
  const int quad = lane >> 4, l16 = lane & 15;

  f32x4 acc[NI][4];
#pragma unroll
  for (int i = 0; i < NI; i++)
#pragma unroll
    for (int j = 0; j < 4; j++) acc[i][j] = (f32x4){0.f, 0.f, 0.f, 0.f};

  const int lrow = lane >> 2;
  const int lcol = (lane & 3) * 8;
  const ushort* gsrc[NC];
  ushort* ldst[NC];
#pragma unroll
  for (int t = 0; t < NC; t++) {
    const int c = w * NC + t;
    if (c < NA) {
      ldst[t] = sa + c * 512;
      gsrc[t] = Ab + (long)(row0 + c * 16 + lrow) * K + lcol;
    } else {
      ldst[t] = sb + (c - NA) * 512;
      gsrc[t] = Bb + (long)(col0 + (c - NA) * 16 + lrow) * K + lcol;
    }
  }

  for (int k0 = 0; k0 < Kend; k0 += 32) {
#pragma unroll
    for (int t = 0; t < NC; t++) async_ld16(gsrc[t] + k0, ldst[t]);
    __syncthreads();
    bf16x8 af[NI], bfr[4];
#pragma unroll
    for (int i = 0; i < NI; i++)
      af[i] = *(const bf16x8*)(sa + (wr * (TM / 2) + i * 16 + l16) * 32 + quad * 8);
#pragma unroll
    for (int j = 0; j < 4; j++)
      bfr[j] = *(const bf16x8*)(sb + (wc * 64 + j * 16 + l16) * 32 + quad * 8);
#pragma unroll
    for (int i = 0; i < NI; i++)
#pragma unroll
      for (int j = 0; j < 4; j++)
        acc[i][j] = __builtin_amdgcn_mfma_f32_16x16x32_bf16(af[i], bfr[j], acc[i][j], 0, 0, 0);
    __syncthreads();
  }

#pragma unroll
  for (int i = 0; i < NI; i++) {
    const int rb = row0 + wr * (TM / 2) + i * 16 + quad * 4;
#pragma unroll
    for (int j = 0; j < 4; j++) {
      const int c = col0 + wc * 64 + j * 16 + l16;
#pragma unroll
      for (int r = 0; r < 4; r++) {
        float v = acc[i][j][r] * scale;
        long off = (long)bz * sC + (long)(rb + r) * N + c;
        if (OUT_BF16)
          ((ushort*)Cv)[off] = f2bf(v);
        else
          ((float*)Cv)[off] = v;
      }
    }
  }
}

// ---------------------------------------------------------------------------
// 256x256 4-phase GEMM, single-read fragments, 2-K-tile unrolled loop
// (T2 swizzle + T3/T4 counted vmcnt + T5 setprio). BK=64, 8 waves (2M x 4N),
// wave tile 128x64, 128 KiB double-buffered LDS.
// LDS layout per buffer/operand: [256 rows][64 k] bf16 with ushort-index
// XOR swizzle idx = row*64 + (col ^ ((row&7)<<3)); realized as linear
// global_load_lds dest + inverse-swizzled global SOURCE + swizzled ds_read
// (rule #21: both-sides-or-neither).
// R5 post-mortem: runtime cbuf made every ds_read address a fresh VGPR
// computation (VALUBusy 20%). The loop now processes 2 K-tiles/iteration
// with LITERAL buffer indices (m201's structure) so all 24 frag reads/K-tile
// collapse to per-lane base + immediate offsets. Odd NT (h-GEMM) takes a
// buffer-0 tail tile.
// B-frags (8 b128 = 32 VGPR) read at phase 0, HELD for the K-tile; phases
// read one A m-pair (4 b128) each and run 16 MFMA. 24 b128/wave/K-tile.
// Staging rounds (2 loads/thread each):
//   R0 = A rows {0-63,128-191}   R1 = B rows {0-31,64-95,128-159,192-223}
//   R2 = B rows +32              R3 = A rows {64-127,192-255}
// Issue for tile t+1: R0+R1 @p0, R2 @p1, R3 @p2. Waits: vmcnt(4) @p0
// (validates cur R3 before p2), vmcnt(2) @p3 (validates next R0,R1,R2
// before next p0). vmcnt(0) never in steady state.
// MASKMODE 2: truncate K to the gates' nonzero range (64-granular).
template <int MASKMODE, bool OUT_BF16>
__global__ __launch_bounds__(512, 2) void gemm256(const ushort* __restrict__ A,
                                                  const ushort* __restrict__ Bt,
                                                  void* __restrict__ Cv, int N, int K,
                                                  long sA, long sB, long sC, float scale) {
  __shared__ __align__(16) ushort lds[2][2][256 * 64];  // [buf][A/B] 128 KiB
  const int bz = blockIdx.z;
  const int row0 = blockIdx.y * 256;
  const int col0 = blockIdx.x * 256;
  int Kend = K;
  if (MASKMODE == 2) {
    int kl = ((row0 + 255) >> 2) + 1;
    Kend = min(K, (kl + 63) & ~63);
  }
  const int NT = Kend >> 6;
  const ushort* Ab = A + (long)bz * sA;
  const ushort* Bb = Bt + (long)bz * sB;

  const int tid = threadIdx.x;
  const int w = tid >> 6, lane = tid & 63;
  const int wr = w >> 2, wc = w & 3;  // 2 x 4 wave grid
  const int quad = lane >> 4, l16 = lane & 15;

  f32x4 acc[8][4];
#pragma unroll
  for (int i = 0; i < 8; i++)
#pragma unroll
    for (int j = 0; j < 4; j++) acc[i][j] = (f32x4){0.f, 0.f, 0.f, 0.f};

  // staging addresses. Each wave-load covers 8 consecutive rows starting at a
  // multiple of 8; lane l -> row base+(l>>3), LDS linear col (l&7)*8 with
  // global col pre-swizzled by the row's low-3-bits: ((l&7)^(l>>3))*8.
  const int lrow = lane >> 3;
  const int lcol = ((lane & 7) ^ lrow) << 3;
  const int bwA = w * 8;                             // A wave row base
  const int bwB = ((w >> 2) << 6) + ((w & 3) << 3);  // B wave row base (R1 set)

  const ushort* a00 = Ab + (long)(row0 + bwA + lrow) * K + lcol;  // rows  0- 63
  const ushort* a01 = a00 + (long)128 * K;                        // rows 128-191
  const ushort* a30 = a00 + (long)64 * K;                         // rows  64-127
  const ushort* a31 = a00 + (long)192 * K;                        // rows 192-255
  const ushort* b10 = Bb + (long)(col0 + bwB + lrow) * K + lcol;  // R1 lo
  const ushort* b11 = b10 + (long)128 * K;                        // R1 hi
  const ushort* b20 = b10 + (long)32 * K;                         // R2 lo
  const ushort* b21 = b10 + (long)160 * K;                        // R2 hi

  const uint dA00 = (uint)(bwA)*64, dA01 = (uint)(bwA + 128) * 64;
  const uint dA30 = (uint)(bwA + 64) * 64, dA31 = (uint)(bwA + 192) * 64;
  const uint dB10 = (uint)(bwB)*64, dB11 = (uint)(bwB + 128) * 64;
  const uint dB20 = (uint)(bwB + 32) * 64, dB21 = (uint)(bwB + 160) * 64;

#define STG_R0(nb, kk)                         \
  do {                                         \
    async_ld16(a00 + (kk), &lds[nb][0][dA00]); \
    async_ld16(a01 + (kk), &lds[nb][0][dA01]); \
  } while (0)
#define STG_R1(nb, kk)                         \
  do {                                         \
    async_ld16(b10 + (kk), &lds[nb][1][dB10]); \
    async_ld16(b11 + (kk), &lds[nb][1][dB11]); \
  } while (0)
#define STG_R2(nb, kk)                         \
  do {                                         \
    async_ld16(b20 + (kk), &lds[nb][1][dB20]); \
    async_ld16(b21 + (kk), &lds[nb][1][dB21]); \
  } while (0)
#define STG_R3(nb, kk)                         \
  do {                                         \
    async_ld16(a30 + (kk), &lds[nb][0][dA30]); \
    async_ld16(a31 + (kk), &lds[nb][0][dA31]); \
  } while (0)

// read A m-pair P (m-frags 2P, 2P+1; rows wr*128 + mf*16), 4 b128. CB literal.
#define LDA_PAIR(CB, P)                                              \
  _Pragma("unroll") for (int mi = 0; mi < 2; mi++) _Pragma("unroll") \
  for (int ks = 0; ks < 2; ks++) {                                   \
    const int row = wr * 128 + ((P)*2 + mi) * 16 + l16;              \
    af[mi][ks] = *(const bf16x8*)&lds[CB][0]                         \
        [row * 64 + ((ks * 32 + quad * 8) ^ ((l16 & 7) << 3))];      \
  }
// read ALL B n-frags (rows wc*64 + n*16), 8 b128, held for the K-tile
#define LDB_ALL(CB)                                                 \
  _Pragma("unroll") for (int n = 0; n < 4; n++) _Pragma("unroll")   \
  for (int ks = 0; ks < 2; ks++) {                                  \
    const int row = wc * 64 + n * 16 + l16;                         \
    bv[n][ks] = *(const bf16x8*)&lds[CB][1]                         \
        [row * 64 + ((ks * 32 + quad * 8) ^ ((l16 & 7) << 3))];     \
  }
#define MM_PAIR(P)                                                   \
  __builtin_amdgcn_s_setprio(1);                                     \
  _Pragma("unroll") for (int mi = 0; mi < 2; mi++) _Pragma("unroll") \
  for (int n = 0; n < 4; n++) _Pragma("unroll")                      \
  for (int ks = 0; ks < 2; ks++)                                     \
    acc[(P)*2 + mi][n] = __builtin_amdgcn_mfma_f32_16x16x32_bf16(    \
        af[mi][ks], bv[n][ks], acc[(P)*2 + mi][n], 0, 0, 0);         \
  __builtin_amdgcn_s_setprio(0);
#define VMC(n) asm volatile("s_waitcnt vmcnt(" #n ")" ::: "memory")
#define SCB __builtin_amdgcn_sched_barrier(0)
#define BAR __builtin_amdgcn_s_barrier()

// one full K-tile, CB = literal buffer index, MORE = stage tile at byte-col KN
#define KTILE(CB, MORE, KN)                                          \
  {                                                                  \
    const bool more_ = (MORE);                                       \
    const int kn_ = (KN);                                            \
    bf16x8 bv[4][2]; /* B held across the K-tile */                  \
    { /* phase 0: B-all + A-pair0; stage next R0,R1; validate R3 */  \
      bf16x8 af[2][2];                                               \
      LDB_ALL(CB)                                                    \
      LDA_PAIR(CB, 0)                                                \
      if (more_) {                                                   \
        STG_R0(CB ^ 1, kn_);                                         \
        STG_R1(CB ^ 1, kn_);                                         \
        VMC(4); /* cur R3 landed; next R0,R1 in flight */            \
      } else {                                                       \
        VMC(0);                                                      \
      }                                                              \
      SCB;                                                           \
      BAR;                                                           \
      MM_PAIR(0)                                                     \
      BAR;                                                           \
    }                                                                \
    { /* phase 1: A-pair1; stage next R2 */                          \
      bf16x8 af[2][2];                                               \
      LDA_PAIR(CB, 1)                                                \
      if (more_) STG_R2(CB ^ 1, kn_);                                \
      BAR;                                                           \
      MM_PAIR(1)                                                     \
      BAR;                                                           \
    }                                                                \
    { /* phase 2: A-pair2 (R3, validated @p0); stage next R3 */      \
      bf16x8 af[2][2];                                               \
      LDA_PAIR(CB, 2)                                                \
      if (more_) STG_R3(CB ^ 1, kn_);                                \
      BAR;                                                           \
      MM_PAIR(2)                                                     \
      BAR;                                                           \
    }                                                                \
    { /* phase 3: A-pair3; validate next R0,R1,R2 for next p0 */     \
      bf16x8 af[2][2];                                               \
      LDA_PAIR(CB, 3)                                                \
      if (more_) {                                                   \
        VMC(2); /* next R0,R1,R2 landed; next R3 in flight */        \
        SCB;                                                         \
      }                                                              \
      BAR;                                                           \
      MM_PAIR(3)                                                     \
      BAR;                                                           \
    }                                                                \
  }

  // prologue: stage K-tile 0 into buffer 0; wait for R0,R1,R2 (R3 in flight)
  STG_R0(0, 0);
  STG_R1(0, 0);
  STG_R2(0, 0);
  STG_R3(0, 0);
  VMC(2);
  SCB;
  BAR;

  // main loop: 2 K-tiles per iteration, literal buffer indices.
  int t = 0;
  for (; t + 2 <= NT; t += 2) {
    KTILE(0, true, (t + 1) << 6);
    KTILE(1, (t + 2) < NT, (t + 2) << 6);
  }
  if (t < NT) {  // odd NT tail: tile NT-1 (even index) lives in buffer 0
    KTILE(0, false, 0);
  }
#undef KTILE
#undef STG_R0
#undef STG_R1
#undef STG_R2
#undef STG_R3
#undef LDA_PAIR
#undef LDB_ALL
#undef MM_PAIR
#undef VMC
#undef SCB
#undef BAR

#pragma unroll
  for (int i = 0; i < 8; i++) {
    const int rb = row0 + wr * 128 + (i >> 2) * 64 + (i & 3) * 16 + quad * 4;
#pragma unroll
    for (int j = 0; j < 4; j++) {
      const int cc = col0 + wc * 64 + (j >> 1) * 32 + (j & 1) * 16 + l16;
#pragma unroll
      for (int r = 0; r < 4; r++) {
        float v = acc[i][j][r] * scale;
        long off = (long)bz * sC + (long)(rb + r) * N + cc;
        if (OUT_BF16)
          ((ushort*)Cv)[off] = f2bf(v);
        else
          ((float*)Cv)[off] = v;
      }
    }
  }
}

// one WAVE per (b,t) row: current-score dot + masked softmax over 513.
__global__ __launch_bounds__(256) void softmax_gate(const ushort* __restrict__ u_bf,
                                                    const float* __restrict__ m_cur,
                                                    const float* __restrict__ scores,
                                                    float* __restrict__ out_gc,
                                                    float* __restrict__ out_attn,
                                                    ushort* __restrict__ gates_bf) {
  const int wv = threadIdx.x >> 6, lane = threadIdx.x & 63;
  const int bt = blockIdx.x * 4 + wv;
  const int t = bt & (T_SZ - 1);
  const ushort* urow = u_bf + (long)bt * D_MODEL;
  const float* mrow = m_cur + (long)bt * D_MODEL;

  float part = 0.f;
#pragma unroll
  for (int c = 0; c < 4; c++) {
    uint4 uv = *(const uint4*)(urow + c * 512 + lane * 8);
    float4 m0 = *(const float4*)(mrow + c * 512 + lane * 8);
    float4 m1 = *(const float4*)(mrow + c * 512 + lane * 8 + 4);
    part += bflo(uv.x) * m0.x + bfhi(uv.x) * m0.y + bflo(uv.y) * m0.z + bfhi(uv.y) * m0.w +
            bflo(uv.z) * m1.x + bfhi(uv.z) * m1.y + bflo(uv.w) * m1.z + bfhi(uv.w) * m1.w;
  }
#pragma unroll
  for (int m = 32; m; m >>= 1) part += __shfl_xor(part, m, 64);
  const float curs = part * 0.022097086912079608f;  // 1/sqrt(2048)

  const int nmax = t >> 2;
  const float* srow = scores + (long)bt * N_SZ;
  float sc[8];
  float lmax = curs;
#pragma unroll
  for (int k = 0; k < 8; k++) {
    const int n = k * 64 + lane;
    sc[k] = srow[n];
    if (n <= nmax) lmax = fmaxf(lmax, sc[k]);
  }
#pragma unroll
  for (int m = 32; m; m >>= 1) lmax = fmaxf(lmax, __shfl_xor(lmax, m, 64));

  float lsum = (lane == 0) ? __expf(curs - lmax) : 0.f;
#pragma unroll
  for (int k = 0; k < 8; k++) {
    const int n = k * 64 + lane;
    sc[k] = (n <= nmax) ? __expf(sc[k] - lmax) : 0.f;
    lsum += sc[k];
  }
#pragma unroll
  for (int m = 32; m; m >>= 1) lsum += __shfl_xor(lsum, m, 64);
  const float inv = 1.f / lsum;

  float* arow = out_attn + (long)bt * (N_SZ + 1);
  ushort* grow = gates_bf + (long)bt * N_SZ;
#pragma unroll
  for (int k = 0; k < 8; k++) {
    const int n = k * 64 + lane;
    const float wgt = sc[k] * inv;
    arow[n] = wgt;
    grow[n] = f2bf(wgt);
  }
  if (lane == 0) {
    const float g = __expf(curs - lmax) * inv;
    arow[N_SZ] = g;
    out_gc[bt] = g;
  }
}

extern "C" void kernel_launch(void* const* d_in, const int* in_sizes, int n_in,
                              void* d_out, int out_size, void* d_ws, size_t ws_size,
                              hipStream_t stream) {
  const float* x = (const float*)d_in[0];        // (B,T,D) fp32
  const float* h_stack = (const float*)d_in[1];  // (B,N,D) fp32
  const float* m_stack = (const float*)d_in[2];  // (B,N,D) fp32
  const float* m_cur = (const float*)d_in[3];    // (B,T,D) fp32
  const float* W = (const float*)d_in[5];        // (D,D) fp32  (d_in[4] = mask, recomputed)

  float* out = (float*)d_out;  // fp32 = reference output dtype
  float* out_h = out;                                 // (B,T,D)
  float* out_gc = out + (long)B_SZ * T_SZ * D_MODEL;  // (B,T,1)
  float* out_attn = out_gc + B_SZ * T_SZ;             // (B,T,N+1)

  // workspace layout (112 MB total)
  char* ws = (char*)d_ws;
  ushort* x_bf = (ushort*)ws;               // B*T*D   = 16,777,216
  ushort* u_bf = x_bf + 16777216;           // B*T*D
  ushort* W_bf = u_bf + 16777216;           // D*D     =  4,194,304
  ushort* ms_bf = W_bf + 4194304;           // B*N*D
  ushort* gates = ms_bf + 4194304;          // B*T*N   =  4,194,304
  ushort* hsT = gates + 4194304;            // B*D*N
  float* scores = (float*)(hsT + 4194304);  // B*T*N fp32

  conv_all<<<12288, 256, 0, stream>>>(x, W, m_stack, x_bf, W_bf, ms_bf);
  transpose_conv<<<dim3(N_SZ / 32, D_MODEL / 32, B_SZ), dim3(32, 8), 0, stream>>>(h_stack, hsT);

  // u = x @ W^T  (M=8192, N=2048, K=2048), out bf16. 256 blocks = 1/CU.
  gemm256<0, true><<<dim3(D_MODEL / 256, (B_SZ * T_SZ) / 256, 1), 512, 0, stream>>>(
      x_bf, W_bf, u_bf, D_MODEL, D_MODEL, 0, 0, 0, 1.0f);

  // scores = u @ m_stack^T * scale  per batch (M=2048, N=512, K=2048), fp32 out.
  // stays on the 128-col-tile path: 320 active blocks vs 64 at 256² tiling.
  gemm_bt<64, 1, false><<<dim3(N_SZ / 128, T_SZ / 64, B_SZ), 256, 0, stream>>>(
      u_bf, ms_bf, scores, N_SZ, D_MODEL, (long)T_SZ * D_MODEL, (long)N_SZ * D_MODEL,
      (long)T_SZ * N_SZ, 0.022097086912079608f);

  softmax_gate<<<(B_SZ * T_SZ) / 4, 256, 0, stream>>>(u_bf, m_cur, scores, out_gc, out_attn,
                                                      gates);

  // h = gates @ hsT^T  per batch (M=2048, N=2048, K truncated 64..512), fp32 out
  gemm256<2, false><<<dim3(D_MODEL / 256, T_SZ / 256, B_SZ), 512, 0, stream>>>(
      gates, hsT, out_h, D_MODEL, N_SZ, (long)T_SZ * N_SZ, (long)D_MODEL * N_SZ,
      (long)T_SZ * D_MODEL, 1.0f);
}

// Round 9
// 349.114 us; speedup vs baseline: 1.1289x; 1.0000x over previous
//
#include <hip/hip_runtime.h>

#define D_MODEL 2048
#define B_SZ 4
#define T_SZ 2048
#define N_SZ 512

typedef __bf16 bf16x8 __attribute__((ext_vector_type(8)));
typedef float f32x4 __attribute__((ext_vector_type(4)));
typedef ushort u16x8 __attribute__((ext_vector_type(8)));

// fp32 -> bf16 round-to-nearest-even
__device__ __forceinline__ ushort f2bf(float f) {
  unsigned u = __float_as_uint(f);
  unsigned r = (u + 0x7fffu + ((u >> 16) & 1u)) >> 16;
  return (ushort)r;
}
__device__ __forceinline__ float bflo(unsigned w) { return __uint_as_float(w << 16); }
__device__ __forceinline__ float bfhi(unsigned w) { return __uint_as_float(w & 0xffff0000u); }

__device__ __forceinline__ void async_ld16(const ushort* g, ushort* l) {
  __builtin_amdgcn_global_load_lds(
      (const __attribute__((address_space(1))) void*)g,
      (__attribute__((address_space(3))) void*)l, 16, 0, 0);
}

// single fused fp32->bf16 conversion for x (8192 blk), W (2048 blk), m_stack (2048 blk)
__global__ __launch_bounds__(256) void conv_all(const float* __restrict__ x,
                                                const float* __restrict__ W,
                                                const float* __restrict__ ms,
                                                ushort* __restrict__ x_bf,
                                                ushort* __restrict__ W_bf,
                                                ushort* __restrict__ ms_bf) {
  const int bid = blockIdx.x;
  const float* src;
  ushort* dst;
  long blk;
  if (bid < 8192) { src = x; dst = x_bf; blk = bid; }
  else if (bid < 10240) { src = W; dst = W_bf; blk = bid - 8192; }
  else { src = ms; dst = ms_bf; blk = bid - 10240; }
  const long i = (blk * 256 + threadIdx.x) * 8;
  float4 a = *(const float4*)(src + i);
  float4 b = *(const float4*)(src + i + 4);
  u16x8 o;
  o[0] = f2bf(a.x); o[1] = f2bf(a.y); o[2] = f2bf(a.z); o[3] = f2bf(a.w);
  o[4] = f2bf(b.x); o[5] = f2bf(b.y); o[6] = f2bf(b.z); o[7] = f2bf(b.w);
  *(u16x8*)(dst + i) = o;
}

// h_stack (B,N,D) fp32 -> hsT (B,D,N) bf16
__global__ __launch_bounds__(256) void transpose_conv(const float* __restrict__ src,
                                                      ushort* __restrict__ dst) {
  __shared__ ushort tile[32][33];
  const int b = blockIdx.z;
  const int n0 = blockIdx.x * 32, d0 = blockIdx.y * 32;
  const int tx = threadIdx.x, ty = threadIdx.y;  // (32,8)
  const float* s = src + (long)b * N_SZ * D_MODEL;
  ushort* d = dst + (long)b * D_MODEL * N_SZ;
#pragma unroll
  for (int r = 0; r < 4; r++)
    tile[ty + r * 8][tx] = f2bf(s[(long)(n0 + ty + r * 8) * D_MODEL + d0 + tx]);
  __syncthreads();
#pragma unroll
  for (int r = 0; r < 4; r++)
    d[(long)(d0 + ty + r * 8) * N_SZ + n0 + tx] = tile[tx][ty + r * 8];
}

// ---------------------------------------------------------------------------
// legacy 128-col tile GEMM — kept for the scores GEMM (N=512 -> needs the
// finer grid for CU coverage). C[M,N] = A[M,K] * Bt[N,K]^T, bf16 in.
// MASKMODE 1: skip tile if col0 > (t_max>>2).
template <int TM, int MASKMODE, bool OUT_BF16>
__global__ __launch_bounds__(256) void gemm_bt(const ushort* __restrict__ A,
                                               const ushort* __restrict__ Bt,
                                               void* __restrict__ Cv, int N, int K,
                                               long sA, long sB, long sC, float scale) {
  constexpr int NA = TM / 16;   // A-tile 1KB chunks
  constexpr int NCH = NA + 8;   // total chunks (B-tile has 8)
  constexpr int NC = NCH / 4;   // chunks per wave
  constexpr int NI = TM / 32;   // i-blocks per wave
  __shared__ __align__(16) ushort sa[TM * 32];
  __shared__ __align__(16) ushort sb[128 * 32];
  const int bz = blockIdx.z;
  const int row0 = blockIdx.y * TM;
  const int col0 = blockIdx.x * 128;
  if (MASKMODE == 1 && col0 > ((row0 + TM - 1) >> 2)) return;
  int Kend = K;
  if (MASKMODE == 2) {
    int kl = ((row0 + TM - 1) >> 2) + 1;
    Kend = min(K, (kl + 31) & ~31);
  }
  const ushort* Ab = A + (long)bz * sA;
  const ushort* Bb = Bt + (long)bz * sB;

  const int tid = threadIdx.x;
  const int w = tid >> 6, lane = tid & 63;
  const int wr = w >> 1, wc = w & 1;
  const int quad = lane >> 4, l16 = lane & 15;

  f32x4 acc[NI][4];
#pragma unroll
  for (int i = 0; i < NI; i++)
#pragma unroll
    for (int j = 0; j < 4; j++) acc[i][j] = (f32x4){0.f, 0.f, 0.f, 0.f};

  const int lrow = lane >> 2;
  const int lcol = (lane & 3) * 8;
  const ushort* gsrc[NC];
  ushort* ldst[NC];
#pragma unroll
  for (int t = 0; t < NC; t++) {
    const int c = w * NC + t;
    if (c < NA) {
      ldst[t] = sa + c * 512;
      gsrc[t] = Ab + (long)(row0 + c * 16 + lrow) * K + lcol;
    } else {
      ldst[t] = sb + (c - NA) * 512;
      gsrc[t] = Bb + (long)(col0 + (c - NA) * 16 + lrow) * K + lcol;
    }
  }

  for (int k0 = 0; k0 < Kend; k0 += 32) {
#pragma unroll
    for (int t = 0; t < NC; t++) async_ld16(gsrc[t] + k0, ldst[t]);
    __syncthreads();
    bf16x8 af[NI], bfr[4];
#pragma unroll
    for (int i = 0; i < NI; i++)
      af[i] = *(const bf16x8*)(sa + (wr * (TM / 2) + i * 16 + l16) * 32 + quad * 8);
#pragma unroll
    for (int j = 0; j < 4; j++)
      bfr[j] = *(const bf16x8*)(sb + (wc * 64 + j * 16 + l16) * 32 + quad * 8);
#pragma unroll
    for (int i = 0; i < NI; i++)
#pragma unroll
      for (int j = 0; j < 4; j++)
        acc[i][j] = __builtin_amdgcn_mfma_f32_16x16x32_bf16(af[i], bfr[j], acc[i][j], 0, 0, 0);
    __syncthreads();
  }

#pragma unroll
  for (int i = 0; i < NI; i++) {
    const int rb = row0 + wr * (TM / 2) + i * 16 + quad * 4;
#pragma unroll
    for (int j = 0; j < 4; j++) {
      const int c = col0 + wc * 64 + j * 16 + l16;
#pragma unroll
      for (int r = 0; r < 4; r++) {
        float v = acc[i][j][r] * scale;
        long off = (long)bz * sC + (long)(rb + r) * N + c;
        if (OUT_BF16)
          ((ushort*)Cv)[off] = f2bf(v);
        else
          ((float*)Cv)[off] = v;
      }
    }
  }
}

// ---------------------------------------------------------------------------
// 256x256 GEMM, 2 phases/K-tile, single-read fragments, 2-K-tile unrolled
// loop, literal buffer indices. T2 swizzle + T4 counted vmcnt + T5 setprio.
// BK=64, 8 waves (2M x 4N), wave tile 128x64, 128 KiB double-buffered LDS.
// LDS layout per buffer/operand: [256 rows][64 k] bf16 with ushort-index
// XOR swizzle idx = row*64 + (col ^ ((row&7)<<3)); realized as linear
// global_load_lds dest + inverse-swizzled global SOURCE + swizzled ds_read
// (rule #21: both-sides-or-neither).
// Phase A: B-all (8 b128, held) + A-pairs 0,1 (8 b128) -> 32 MFMA.
// Phase B: A-pairs 2,3 (8 b128) -> 32 MFMA.
// R8 post-mortem (CORRECTNESS): waits must validate each phase's INPUT one
// phase ahead of its reads. Queue trace (oldest first), steady state at
// entry to tile t phase A: [t R3 (2)]. Waits:
//   phase A: issue next R0,R1,R2 (8 outstanding) -> VMC(6) drains cur R3
//            (validated before the barrier preceding phase B's R3-reads).
//   phase B: issue next R3 (8 outstanding) -> VMC(2) drains next R0-R2
//            (validated before next tile's phase-A reads).
// Tail (no staging): phase A VMC(0) (cur R3); phase B no wait.
// R8's VMC(8)/VMC(8) validated nothing -> race -> FAILED. Each load keeps
// one full phase (~1300cyc) of latency cover; vmcnt(0) never in steady state.
// Staging rounds (2 loads/thread each):
//   R0 = A rows {0-63,128-191}   R1 = B rows {0-31,64-95,128-159,192-223}
//   R2 = B rows +32              R3 = A rows {64-127,192-255}
// MASKMODE 2: truncate K to the gates' nonzero range (64-granular).
template <int MASKMODE, bool OUT_BF16>
__global__ __launch_bounds__(512, 2) void gemm256(const ushort* __restrict__ A,
                                                  const ushort* __restrict__ Bt,
                                                  void* __restrict__ Cv, int N, int K,
                                                  long sA, long sB, long sC, float scale) {
  __shared__ __align__(16) ushort lds[2][2][256 * 64];  // [buf][A/B] 128 KiB
  const int bz = blockIdx.z;
  const int row0 = blockIdx.y * 256;
  const int col0 = blockIdx.x * 256;
  int Kend = K;
  if (MASKMODE == 2) {
    int kl = ((row0 + 255) >> 2) + 1;
    Kend = min(K, (kl + 63) & ~63);
  }
  const int NT = Kend >> 6;
  const ushort* Ab = A + (long)bz * sA;
  const ushort* Bb = Bt + (long)bz * sB;

  const int tid = threadIdx.x;
  const int w = tid >> 6, lane = tid & 63;
  const int wr = w >> 2, wc = w & 3;  // 2 x 4 wave grid
  const int quad = lane >> 4, l16 = lane & 15;

  f32x4 acc[8][4];
#pragma unroll
  for (int i = 0; i < 8; i++)
#pragma unroll
    for (int j = 0; j < 4; j++) acc[i][j] = (f32x4){0.f, 0.f, 0.f, 0.f};

  // staging addresses. Each wave-load covers 8 consecutive rows starting at a
  // multiple of 8; lane l -> row base+(l>>3), LDS linear col (l&7)*8 with
  // global col pre-swizzled by the row's low-3-bits: ((l&7)^(l>>3))*8.
  const int lrow = lane >> 3;
  const int lcol = ((lane & 7) ^ lrow) << 3;
  const int bwA = w * 8;                             // A wave row base
  const int bwB = ((w >> 2) << 6) + ((w & 3) << 3);  // B wave row base (R1 set)

  const ushort* a00 = Ab + (long)(row0 + bwA + lrow) * K + lcol;  // rows  0- 63
  const ushort* a01 = a00 + (long)128 * K;                        // rows 128-191
  const ushort* a30 = a00 + (long)64 * K;                         // rows  64-127
  const ushort* a31 = a00 + (long)192 * K;                        // rows 192-255
  const ushort* b10 = Bb + (long)(col0 + bwB + lrow) * K + lcol;  // R1 lo
  const ushort* b11 = b10 + (long)128 * K;                        // R1 hi
  const ushort* b20 = b10 + (long)32 * K;                         // R2 lo
  const ushort* b21 = b10 + (long)160 * K;                        // R2 hi

  const uint dA00 = (uint)(bwA)*64, dA01 = (uint)(bwA + 128) * 64;
  const uint dA30 = (uint)(bwA + 64) * 64, dA31 = (uint)(bwA + 192) * 64;
  const uint dB10 = (uint)(bwB)*64, dB11 = (uint)(bwB + 128) * 64;
  const uint dB20 = (uint)(bwB + 32) * 64, dB21 = (uint)(bwB + 160) * 64;

#define STG_R0(nb, kk)                         \
  do {                                         \
    async_ld16(a00 + (kk), &lds[nb][0][dA00]); \
    async_ld16(a01 + (kk), &lds[nb][0][dA01]); \
  } while (0)
#define STG_R1(nb, kk)                         \
  do {                                         \
    async_ld16(b10 + (kk), &lds[nb][1][dB10]); \
    async_ld16(b11 + (kk), &lds[nb][1][dB11]); \
  } while (0)
#define STG_R2(nb, kk)                         \
  do {                                         \
    async_ld16(b20 + (kk), &lds[nb][1][dB20]); \
    async_ld16(b21 + (kk), &lds[nb][1][dB21]); \
  } while (0)
#define STG_R3(nb, kk)                         \
  do {                                         \
    async_ld16(a30 + (kk), &lds[nb][0][dA30]); \
    async_ld16(a31 + (kk), &lds[nb][0][dA31]); \
  } while (0)

// read A m-pair P (m-frags 2P, 2P+1; rows wr*128 + mf*16) into DST, 4 b128.
#define LDA_PAIR(CB, P, DST)                                         \
  _Pragma("unroll") for (int mi = 0; mi < 2; mi++) _Pragma("unroll") \
  for (int ks = 0; ks < 2; ks++) {                                   \
    const int row = wr * 128 + ((P)*2 + mi) * 16 + l16;              \
    DST[mi][ks] = *(const bf16x8*)&lds[CB][0]                        \
        [row * 64 + ((ks * 32 + quad * 8) ^ ((l16 & 7) << 3))];      \
  }
// read ALL B n-frags (rows wc*64 + n*16), 8 b128, held for the K-tile
#define LDB_ALL(CB)                                                 \
  _Pragma("unroll") for (int n = 0; n < 4; n++) _Pragma("unroll")   \
  for (int ks = 0; ks < 2; ks++) {                                  \
    const int row = wc * 64 + n * 16 + l16;                         \
    bv[n][ks] = *(const bf16x8*)&lds[CB][1]                         \
        [row * 64 + ((ks * 32 + quad * 8) ^ ((l16 & 7) << 3))];     \
  }
// 16 MFMA for pair P from SRC (no setprio; caller wraps the region)
#define MMX(P, SRC)                                                  \
  _Pragma("unroll") for (int mi = 0; mi < 2; mi++) _Pragma("unroll") \
  for (int n = 0; n < 4; n++) _Pragma("unroll")                      \
  for (int ks = 0; ks < 2; ks++)                                     \
    acc[(P)*2 + mi][n] = __builtin_amdgcn_mfma_f32_16x16x32_bf16(    \
        SRC[mi][ks], bv[n][ks], acc[(P)*2 + mi][n], 0, 0, 0);
#define VMC(n) asm volatile("s_waitcnt vmcnt(" #n ")" ::: "memory")
#define SCB __builtin_amdgcn_sched_barrier(0)
#define BAR __builtin_amdgcn_s_barrier()

// one full K-tile, CB = literal buffer index, MORE = stage tile at byte-col KN
#define KTILE(CB, MORE, KN)                                           \
  {                                                                   \
    const bool more_ = (MORE);                                        \
    const int kn_ = (KN);                                             \
    bf16x8 bv[4][2]; /* B held across the K-tile */                   \
    { /* phase A: B-all + A-pairs 0,1 -> 32 MFMA */                   \
      bf16x8 af0[2][2], af1[2][2];                                    \
      LDB_ALL(CB)                                                     \
      LDA_PAIR(CB, 0, af0)                                            \
      LDA_PAIR(CB, 1, af1)                                            \
      if (more_) {                                                    \
        STG_R0(CB ^ 1, kn_);                                          \
        STG_R1(CB ^ 1, kn_);                                          \
        STG_R2(CB ^ 1, kn_);                                          \
        VMC(6); /* drains cur R3 (for phase B); 6 fresh in flight */  \
      } else {                                                        \
        VMC(0); /* drains cur R3 */                                   \
      }                                                               \
      SCB;                                                            \
      BAR;                                                            \
      __builtin_amdgcn_s_setprio(1);                                  \
      MMX(0, af0)                                                     \
      MMX(1, af1)                                                     \
      __builtin_amdgcn_s_setprio(0);                                  \
      BAR;                                                            \
    }                                                                 \
    { /* phase B: A-pairs 2,3 -> 32 MFMA */                           \
      bf16x8 af2[2][2], af3[2][2];                                    \
      LDA_PAIR(CB, 2, af2)                                            \
      LDA_PAIR(CB, 3, af3)                                            \
      if (more_) {                                                    \
        STG_R3(CB ^ 1, kn_);                                          \
        VMC(2); /* drains next R0-R2 (for next phase A) */            \
        SCB;                                                          \
      }                                                               \
      BAR;                                                            \
      __builtin_amdgcn_s_setprio(1);                                  \
      MMX(2, af2)                                                     \
      MMX(3, af3)                                                     \
      __builtin_amdgcn_s_setprio(0);                                  \
      BAR;                                                            \
    }                                                                 \
  }

  // prologue: stage K-tile 0 into buffer 0; VMC(2) validates R0-R2 (R3 in
  // flight -> matches steady-state entry to phase A)
  STG_R0(0, 0);
  STG_R1(0, 0);
  STG_R2(0, 0);
  STG_R3(0, 0);
  VMC(2);
  SCB;
  BAR;

  // main loop: 2 K-tiles per iteration, literal buffer indices.
  int t = 0;
  for (; t + 2 <= NT; t += 2) {
    KTILE(0, true, (t + 1) << 6);
    KTILE(1, (t + 2) < NT, (t + 2) << 6);
  }
  if (t < NT) {  // odd NT tail: tile NT-1 (even index) lives in buffer 0
    KTILE(0, false, 0);
  }
#undef KTILE
#undef STG_R0
#undef STG_R1
#undef STG_R2
#undef STG_R3
#undef LDA_PAIR
#undef LDB_ALL
#undef MMX
#undef VMC
#undef SCB
#undef BAR

#pragma unroll
  for (int i = 0; i < 8; i++) {
    const int rb = row0 + wr * 128 + (i >> 2) * 64 + (i & 3) * 16 + quad * 4;
#pragma unroll
    for (int j = 0; j < 4; j++) {
      const int cc = col0 + wc * 64 + (j >> 1) * 32 + (j & 1) * 16 + l16;
#pragma unroll
      for (int r = 0; r < 4; r++) {
        float v = acc[i][j][r] * scale;
        long off = (long)bz * sC + (long)(rb + r) * N + cc;
        if (OUT_BF16)
          ((ushort*)Cv)[off] = f2bf(v);
        else
          ((float*)Cv)[off] = v;
      }
    }
  }
}

// one WAVE per (b,t) row: current-score dot + masked softmax over 513.
__global__ __launch_bounds__(256) void softmax_gate(const ushort* __restrict__ u_bf,
                                                    const float* __restrict__ m_cur,
                                                    const float* __restrict__ scores,
                                                    float* __restrict__ out_gc,
                                                    float* __restrict__ out_attn,
                                                    ushort* __restrict__ gates_bf) {
  const int wv = threadIdx.x >> 6, lane = threadIdx.x & 63;
  const int bt = blockIdx.x * 4 + wv;
  const int t = bt & (T_SZ - 1);
  const ushort* urow = u_bf + (long)bt * D_MODEL;
  const float* mrow = m_cur + (long)bt * D_MODEL;

  float part = 0.f;
#pragma unroll
  for (int c = 0; c < 4; c++) {
    uint4 uv = *(const uint4*)(urow + c * 512 + lane * 8);
    float4 m0 = *(const float4*)(mrow + c * 512 + lane * 8);
    float4 m1 = *(const float4*)(mrow + c * 512 + lane * 8 + 4);
    part += bflo(uv.x) * m0.x + bfhi(uv.x) * m0.y + bflo(uv.y) * m0.z + bfhi(uv.y) * m0.w +
            bflo(uv.z) * m1.x + bfhi(uv.z) * m1.y + bflo(uv.w) * m1.z + bfhi(uv.w) * m1.w;
  }
#pragma unroll
  for (int m = 32; m; m >>= 1) part += __shfl_xor(part, m, 64);
  const float curs = part * 0.022097086912079608f;  // 1/sqrt(2048)

  const int nmax = t >> 2;
  const float* srow = scores + (long)bt * N_SZ;
  float sc[8];
  float lmax = curs;
#pragma unroll
  for (int k = 0; k < 8; k++) {
    const int n = k * 64 + lane;
    sc[k] = srow[n];
    if (n <= nmax) lmax = fmaxf(lmax, sc[k]);
  }
#pragma unroll
  for (int m = 32; m; m >>= 1) lmax = fmaxf(lmax, __shfl_xor(lmax, m, 64));

  float lsum = (lane == 0) ? __expf(curs - lmax) : 0.f;
#pragma unroll
  for (int k = 0; k < 8; k++) {
    const int n = k * 64 + lane;
    sc[k] = (n <= nmax) ? __expf(sc[k] - lmax) : 0.f;
    lsum += sc[k];
  }
#pragma unroll
  for (int m = 32; m; m >>= 1) lsum += __shfl_xor(lsum, m, 64);
  const float inv = 1.f / lsum;

  float* arow = out_attn + (long)bt * (N_SZ + 1);
  ushort* grow = gates_bf + (long)bt * N_SZ;
#pragma unroll
  for (int k = 0; k < 8; k++) {
    const int n = k * 64 + lane;
    const float wgt = sc[k] * inv;
    arow[n] = wgt;
    grow[n] = f2bf(wgt);
  }
  if (lane == 0) {
    const float g = __expf(curs - lmax) * inv;
    arow[N_SZ] = g;
    out_gc[bt] = g;
  }
}

extern "C" void kernel_launch(void* const* d_in, const int* in_sizes, int n_in,
                              void* d_out, int out_size, void* d_ws, size_t ws_size,
                              hipStream_t stream) {
  const float* x = (const float*)d_in[0];        // (B,T,D) fp32
  const float* h_stack = (const float*)d_in[1];  // (B,N,D) fp32
  const float* m_stack = (const float*)d_in[2];  // (B,N,D) fp32
  const float* m_cur = (const float*)d_in[3];    // (B,T,D) fp32
  const float* W = (const float*)d_in[5];        // (D,D) fp32  (d_in[4] = mask, recomputed)

  float* out = (float*)d_out;  // fp32 = reference output dtype
  float* out_h = out;                                 // (B,T,D)
  float* out_gc = out + (long)B_SZ * T_SZ * D_MODEL;  // (B,T,1)
  float* out_attn = out_gc + B_SZ * T_SZ;             // (B,T,N+1)

  // workspace layout (112 MB total)
  char* ws = (char*)d_ws;
  ushort* x_bf = (ushort*)ws;               // B*T*D   = 16,777,216
  ushort* u_bf = x_bf + 16777216;           // B*T*D
  ushort* W_bf = u_bf + 16777216;           // D*D     =  4,194,304
  ushort* ms_bf = W_bf + 4194304;           // B*N*D
  ushort* gates = ms_bf + 4194304;          // B*T*N   =  4,194,304
  ushort* hsT = gates + 4194304;            // B*D*N
  float* scores = (float*)(hsT + 4194304);  // B*T*N fp32

  conv_all<<<12288, 256, 0, stream>>>(x, W, m_stack, x_bf, W_bf, ms_bf);
  transpose_conv<<<dim3(N_SZ / 32, D_MODEL / 32, B_SZ), dim3(32, 8), 0, stream>>>(h_stack, hsT);

  // u = x @ W^T  (M=8192, N=2048, K=2048), out bf16. 256 blocks = 1/CU.
  gemm256<0, true><<<dim3(D_MODEL / 256, (B_SZ * T_SZ) / 256, 1), 512, 0, stream>>>(
      x_bf, W_bf, u_bf, D_MODEL, D_MODEL, 0, 0, 0, 1.0f);

  // scores = u @ m_stack^T * scale  per batch (M=2048, N=512, K=2048), fp32 out.
  // stays on the 128-col-tile path: 320 active blocks vs 64 at 256² tiling.
  gemm_bt<64, 1, false><<<dim3(N_SZ / 128, T_SZ / 64, B_SZ), 256, 0, stream>>>(
      u_bf, ms_bf, scores, N_SZ, D_MODEL, (long)T_SZ * D_MODEL, (long)N_SZ * D_MODEL,
      (long)T_SZ * N_SZ, 0.022097086912079608f);

  softmax_gate<<<(B_SZ * T_SZ) / 4, 256, 0, stream>>>(u_bf, m_cur, scores, out_gc, out_attn,
                                                      gates);

  // h = gates @ hsT^T  per batch (M=2048, N=2048, K truncated 64..512), fp32 out
  gemm256<2, false><<<dim3(D_MODEL / 256, T_SZ / 256, B_SZ), 512, 0, stream>>>(
      gates, hsT, out_h, D_MODEL, N_SZ, (long)T_SZ * N_SZ, (long)D_MODEL * N_SZ,
      (long)T_SZ * D_MODEL, 1.0f);
}